// Round 6
// baseline (3413.416 us; speedup 1.0000x reference)
//
#include <hip/hip_runtime.h>
#include <cstddef>

#define DIN 128
#define DD 64

typedef unsigned short bfu;   // raw bf16 bits

static __device__ __forceinline__ float bf2f(bfu u) {
    union { unsigned int i; float f; } v; v.i = ((unsigned int)u) << 16; return v.f;
}
static __device__ __forceinline__ bfu f2bf(float f) {
    union { float f; unsigned int i; } v; v.f = f;
    unsigned int r = v.i + 0x7FFFu + ((v.i >> 16) & 1u);   // round-nearest-even
    return (bfu)(r >> 16);
}
static __device__ __forceinline__ float4 bf4_to_f4(ushort4 u) {
    return make_float4(bf2f(u.x), bf2f(u.y), bf2f(u.z), bf2f(u.w));
}
static __device__ __forceinline__ ushort4 f4_to_bf4(float4 f) {
    ushort4 u; u.x = f2bf(f.x); u.y = f2bf(f.y); u.z = f2bf(f.z); u.w = f2bf(f.w); return u;
}
static __device__ __forceinline__ float sigmoidf_(float x) {
    return 1.0f / (1.0f + __expf(-x));
}
static __device__ __forceinline__ float readlane_f(float v, int lane) {
    return __uint_as_float(__builtin_amdgcn_readlane(__float_as_uint(v), lane));
}

// ---------------------------------------------------------------------------
// h0 = nodes_feat @ W_h + b_h   [N,128]@[128,64] -> f32
// ---------------------------------------------------------------------------
__global__ __launch_bounds__(256) void embed_h_v6(
    const float* __restrict__ x, const float* __restrict__ Wh,
    const float* __restrict__ bh, float* __restrict__ h, int N)
{
    __shared__ float w[DIN][DD];    // 32 KB
    __shared__ float xs[32][DIN];   // 16 KB
    for (int i = threadIdx.x; i < DIN * DD / 4; i += 256)
        ((float4*)w)[i] = ((const float4*)Wh)[i];
    int row0 = blockIdx.x * 32;
    for (int i = threadIdx.x; i < 32 * DIN / 4; i += 256) {
        int r = i >> 5, k = (i & 31) * 4;
        int row = row0 + r;
        float4 v = make_float4(0.f, 0.f, 0.f, 0.f);
        if (row < N) v = *(const float4*)(x + (size_t)row * DIN + k);
        *(float4*)(&xs[r][k]) = v;
    }
    __syncthreads();
    int rl = threadIdx.x >> 6;
    int c  = threadIdx.x & 63;
    float b = bh[c];
    for (int rr = 0; rr < 8; ++rr) {
        int r = rl * 8 + rr;
        int row = row0 + r;
        if (row >= N) break;
        float acc = b;
        #pragma unroll
        for (int k = 0; k < DIN; k += 4) {
            float4 xv = *(const float4*)(&xs[r][k]);
            acc += xv.x * w[k][c] + xv.y * w[k+1][c] + xv.z * w[k+2][c] + xv.w * w[k+3][c];
        }
        h[(size_t)row * DD + c] = acc;
    }
}

// ---------------------------------------------------------------------------
// CSR build (by dst): histogram -> 3-phase exclusive scan -> scatter
// ---------------------------------------------------------------------------
__global__ void csr_hist_v6(const int* __restrict__ dst, int* __restrict__ counts, int E)
{
    for (int i = blockIdx.x * blockDim.x + threadIdx.x; i < E; i += gridDim.x * blockDim.x)
        atomicAdd(&counts[dst[i]], 1);
}

__global__ void csr_scan_a_v6(const int* __restrict__ counts, int* __restrict__ part,
                              int M, int CH)
{
    __shared__ int sd[256];
    int b = blockIdx.x, t = threadIdx.x;
    int idx = b * CH + t;
    int v = (t < CH && idx < M) ? counts[idx] : 0;
    sd[t] = v; __syncthreads();
    for (int off = 128; off > 0; off >>= 1) {
        if (t < off) sd[t] += sd[t + off];
        __syncthreads();
    }
    if (t == 0) part[b] = sd[0];
}

__global__ void csr_scan_b_v6(int* __restrict__ part)
{
    __shared__ int sd[256];
    int t = threadIdx.x;
    int v = part[t];
    sd[t] = v; __syncthreads();
    for (int off = 1; off < 256; off <<= 1) {
        int u = (t >= off) ? sd[t - off] : 0;
        __syncthreads();
        sd[t] += u;
        __syncthreads();
    }
    part[t] = sd[t] - v;   // exclusive
}

__global__ void csr_scan_c_v6(const int* __restrict__ counts, const int* __restrict__ part,
                              int* __restrict__ offsets, int* __restrict__ cursor,
                              int M, int CH)
{
    __shared__ int sd[256];
    int b = blockIdx.x, t = threadIdx.x;
    int idx = b * CH + t;
    int v = (t < CH && idx < M) ? counts[idx] : 0;
    sd[t] = v; __syncthreads();
    for (int off = 1; off < 256; off <<= 1) {
        int u = (t >= off) ? sd[t - off] : 0;
        __syncthreads();
        sd[t] += u;
        __syncthreads();
    }
    int excl = sd[t] - v + part[b];
    if (t < CH && idx < M) { offsets[idx] = excl; cursor[idx] = excl; }
}

__global__ void csr_scatter_v6(const int* __restrict__ dst, int* __restrict__ cursor,
                               int* __restrict__ csr_eid, int E)
{
    for (int i = blockIdx.x * blockDim.x + threadIdx.x; i < E; i += gridDim.x * blockDim.x) {
        int p = atomicAdd(&cursor[dst[i]], 1);
        csr_eid[p] = i;
    }
}

// src_p[j] = (ushort)esrc[csr_eid[j]]; enorm_p[j] = enorm[csr_eid[j]]
__global__ void perm_build_v6(const int* __restrict__ csr_eid, const int* __restrict__ esrc,
                              const float* __restrict__ enorm,
                              unsigned short* __restrict__ src_p,
                              float* __restrict__ enorm_p, int E)
{
    for (int i = blockIdx.x * blockDim.x + threadIdx.x; i < E; i += gridDim.x * blockDim.x) {
        int eid = csr_eid[i];
        src_p[i] = (unsigned short)esrc[eid];
        enorm_p[i] = enorm[eid];
    }
}

// e_p[j] = bf16(edges_feat[csr_eid[j]] * W_e + b_e)
__global__ __launch_bounds__(256) void embed_e_perm_v6(
    const float* __restrict__ ef, const float* __restrict__ We,
    const float* __restrict__ be, const int* __restrict__ csr_eid,
    bfu* __restrict__ e, int E)
{
    int c = (threadIdx.x & 15) * 4;
    float4 w = *(const float4*)(We + c);
    float4 b = *(const float4*)(be + c);
    int total = E * 16;
    int stride = gridDim.x * blockDim.x;
    for (int u = blockIdx.x * blockDim.x + threadIdx.x; u < total; u += stride) {
        int j = u >> 4;
        float f = ef[csr_eid[j]];
        float4 o;
        o.x = f * w.x + b.x; o.y = f * w.y + b.y;
        o.z = f * w.z + b.z; o.w = f * w.w + b.w;
        *(ushort4*)(e + (size_t)j * DD + c) = f4_to_bf4(o);
    }
}

// ---------------------------------------------------------------------------
// Ah/Bh/Dh = h @ W{a,b,d} + bias.  192 threads: one wave per matrix.
// ---------------------------------------------------------------------------
__global__ __launch_bounds__(192) void node_mm3_v6(
    const float* __restrict__ h,
    const float* __restrict__ Wa, const float* __restrict__ ba,
    const float* __restrict__ Wb, const float* __restrict__ bbv,
    const float* __restrict__ Wd, const float* __restrict__ bd,
    bfu* __restrict__ Ah, bfu* __restrict__ Bh, bfu* __restrict__ Dh, int N)
{
    __shared__ float hs[64][DD];   // 16 KB
    int row0 = blockIdx.x * 64;
    for (int i = threadIdx.x; i < 64 * 16; i += 192) {
        int r = i >> 4, cc = (i & 15) * 4;
        int row = row0 + r;
        float4 v = make_float4(0.f, 0.f, 0.f, 0.f);
        if (row < N) v = *(const float4*)(h + (size_t)row * DD + cc);
        *(float4*)(&hs[r][cc]) = v;
    }
    __syncthreads();
    int m = threadIdx.x / 64;
    int c = threadIdx.x & 63;
    const float* W    = (m == 0) ? Wa : (m == 1) ? Wb : Wd;
    const float* bias = (m == 0) ? ba : (m == 1) ? bbv : bd;
    bfu*         Out  = (m == 0) ? Ah : (m == 1) ? Bh : Dh;
    float wcol[DD];
    #pragma unroll
    for (int k = 0; k < DD; ++k) wcol[k] = W[k * DD + c];
    float b = bias[c];
    int rmax = (N - row0 < 64) ? (N - row0) : 64;
    for (int r = 0; r < rmax; ++r) {
        float acc = b;
        #pragma unroll
        for (int k = 0; k < DD; k += 4) {
            float4 hv = *(const float4*)(&hs[r][k]);
            acc += hv.x * wcol[k] + hv.y * wcol[k+1] + hv.z * wcol[k+2] + hv.w * wcol[k+3];
        }
        Out[(size_t)(row0 + r) * DD + c] = f2bf(acc);
    }
}

// ---------------------------------------------------------------------------
// ec_gemm: per 64-edge chunk: [optional fused BN-apply of PREVIOUS layer:
// e_new = e_old + relu(g*(es-mu)*istd+bt), written back to e] then
// ecs[j] = bf16(e_new @ Wc + bc).  All sequential traffic; es read from ecs
// in place (read-before-write within the chunk, same thread ordering safe).
// LDS row swizzle (rot = 4*(r&15)) makes the GEMM reads bank-conflict-free.
// ---------------------------------------------------------------------------
__global__ __launch_bounds__(256) void ec_gemm_v6(
    bfu* __restrict__ e, bfu* __restrict__ ecs,
    const float* __restrict__ Wc, const float* __restrict__ bc,
    const float* __restrict__ bnp, const float* __restrict__ gamma,
    const float* __restrict__ beta, int apply, int E)
{
    __shared__ float wc[DD][DD];    // 16 KB
    __shared__ float bcs[DD];
    __shared__ float els[64][DD];   // 16 KB (swizzled)
    for (int i = threadIdx.x; i < DD * DD / 4; i += 256)
        ((float4*)wc)[i] = ((const float4*)Wc)[i];
    if (threadIdx.x < DD) bcs[threadIdx.x] = bc[threadIdx.x];

    int el = threadIdx.x >> 4;          // 0..15
    int c  = (threadIdx.x & 15) * 4;    // channel group (stable across i-loop: 256%16==0)
    float4 mu = make_float4(0,0,0,0), isd = mu, g = mu, bt = mu;
    if (apply) {
        mu  = *(const float4*)(bnp + c);
        isd = *(const float4*)(bnp + DD + c);
        g   = *(const float4*)(gamma + c);
        bt  = *(const float4*)(beta + c);
    }

    int stride = gridDim.x * 64;
    for (int base = blockIdx.x * 64; base < E; base += stride) {
        __syncthreads();
        for (int i = threadIdx.x; i < 64 * 16; i += 256) {
            int r = i >> 4;
            int j = base + r;
            int sc = (c + 4 * (r & 15)) & 63;
            float4 v = make_float4(0.f, 0.f, 0.f, 0.f);
            if (j < E) {
                size_t off = (size_t)j * DD + c;
                v = bf4_to_f4(*(const ushort4*)(e + off));
                if (apply) {
                    float4 es4 = bf4_to_f4(*(const ushort4*)(ecs + off));
                    v.x += fmaxf(g.x * (es4.x - mu.x) * isd.x + bt.x, 0.f);
                    v.y += fmaxf(g.y * (es4.y - mu.y) * isd.y + bt.y, 0.f);
                    v.z += fmaxf(g.z * (es4.z - mu.z) * isd.z + bt.z, 0.f);
                    v.w += fmaxf(g.w * (es4.w - mu.w) * isd.w + bt.w, 0.f);
                    *(ushort4*)(e + off) = f4_to_bf4(v);
                }
            }
            *(float4*)(&els[r][sc]) = v;
        }
        __syncthreads();
        // GEMM: thread -> rows el, el+16, el+32, el+48; cols c..c+3
        float4 a0 = *(const float4*)(bcs + c);
        float4 a1 = a0, a2 = a0, a3 = a0;
        int rot = 4 * el;
        #pragma unroll
        for (int k = 0; k < DD; k += 4) {
            int kk = (k + rot) & 63;
            float4 ev0 = *(const float4*)(&els[el][kk]);
            float4 ev1 = *(const float4*)(&els[el + 16][kk]);
            float4 ev2 = *(const float4*)(&els[el + 32][kk]);
            float4 ev3 = *(const float4*)(&els[el + 48][kk]);
            float4 w0 = *(const float4*)(&wc[k][c]);
            float4 w1 = *(const float4*)(&wc[k+1][c]);
            float4 w2 = *(const float4*)(&wc[k+2][c]);
            float4 w3 = *(const float4*)(&wc[k+3][c]);
            a0.x += ev0.x*w0.x + ev0.y*w1.x + ev0.z*w2.x + ev0.w*w3.x;
            a0.y += ev0.x*w0.y + ev0.y*w1.y + ev0.z*w2.y + ev0.w*w3.y;
            a0.z += ev0.x*w0.z + ev0.y*w1.z + ev0.z*w2.z + ev0.w*w3.z;
            a0.w += ev0.x*w0.w + ev0.y*w1.w + ev0.z*w2.w + ev0.w*w3.w;
            a1.x += ev1.x*w0.x + ev1.y*w1.x + ev1.z*w2.x + ev1.w*w3.x;
            a1.y += ev1.x*w0.y + ev1.y*w1.y + ev1.z*w2.y + ev1.w*w3.y;
            a1.z += ev1.x*w0.z + ev1.y*w1.z + ev1.z*w2.z + ev1.w*w3.z;
            a1.w += ev1.x*w0.w + ev1.y*w1.w + ev1.z*w2.w + ev1.w*w3.w;
            a2.x += ev2.x*w0.x + ev2.y*w1.x + ev2.z*w2.x + ev2.w*w3.x;
            a2.y += ev2.x*w0.y + ev2.y*w1.y + ev2.z*w2.y + ev2.w*w3.y;
            a2.z += ev2.x*w0.z + ev2.y*w1.z + ev2.z*w2.z + ev2.w*w3.z;
            a2.w += ev2.x*w0.w + ev2.y*w1.w + ev2.z*w2.w + ev2.w*w3.w;
            a3.x += ev3.x*w0.x + ev3.y*w1.x + ev3.z*w2.x + ev3.w*w3.x;
            a3.y += ev3.x*w0.y + ev3.y*w1.y + ev3.z*w2.y + ev3.w*w3.y;
            a3.z += ev3.x*w0.z + ev3.y*w1.z + ev3.z*w2.z + ev3.w*w3.z;
            a3.w += ev3.x*w0.w + ev3.y*w1.w + ev3.z*w2.w + ev3.w*w3.w;
        }
        int j0 = base + el;
        if (j0 < E)      *(ushort4*)(ecs + (size_t)j0 * DD + c)        = f4_to_bf4(a0);
        if (j0+16 < E)   *(ushort4*)(ecs + (size_t)(j0+16) * DD + c)   = f4_to_bf4(a1);
        if (j0+32 < E)   *(ushort4*)(ecs + (size_t)(j0+32) * DD + c)   = f4_to_bf4(a2);
        if (j0+48 < E)   *(ushort4*)(ecs + (size_t)(j0+48) * DD + c)   = f4_to_bf4(a3);
    }
}

// ---------------------------------------------------------------------------
// fused node-centric accumulation: one WAVE per dst node, lane = channel.
// Eh[n] computed on the fly (readlane matvec over f32 h row); per edge j:
// er = ecs[j] + Dh[src] + Eh; num/den in registers; es = er*enorm written
// back into ecs (in place) for the next layer's fused BN-apply.
// stats: [0:64) sum es | [64:128) es^2 | [128:192) x | [192:256) x^2
// ---------------------------------------------------------------------------
__global__ __launch_bounds__(256) void fused_accum_v6(
    bfu* __restrict__ ecs,
    const bfu* __restrict__ Ah, const bfu* __restrict__ Bh, const bfu* __restrict__ Dh,
    const float* __restrict__ h, const float* __restrict__ We, const float* __restrict__ be,
    const int* __restrict__ coffs, const unsigned short* __restrict__ src_p,
    const float* __restrict__ enorm_p, const float* __restrict__ nnorm,
    float* __restrict__ hraw, float* __restrict__ stats, int N, int store_es)
{
    __shared__ float red[4][4][DD];
    int wid = threadIdx.x >> 6;
    int c   = threadIdx.x & 63;
    float wcol[DD];
    #pragma unroll
    for (int k = 0; k < DD; ++k) wcol[k] = We[k * DD + c];
    float bec = be[c];
    float se = 0.f, se2 = 0.f, sh = 0.f, sh2 = 0.f;

    int gw = blockIdx.x * 4 + wid;
    int gstride = gridDim.x * 4;
    for (int n = gw; n < N; n += gstride) {
        int j0 = coffs[n], j1 = coffs[n + 1];
        float hv = h[(size_t)n * DD + c];
        float e0 = bec, e1 = 0.f, e2 = 0.f, e3 = 0.f;
        #pragma unroll
        for (int k = 0; k < DD; k += 4) {
            e0 += readlane_f(hv, k)     * wcol[k];
            e1 += readlane_f(hv, k + 1) * wcol[k + 1];
            e2 += readlane_f(hv, k + 2) * wcol[k + 2];
            e3 += readlane_f(hv, k + 3) * wcol[k + 3];
        }
        float ehv = (e0 + e1) + (e2 + e3);
        float num = 0.f, den = 0.f;
        for (int j = j0; j < j1; ++j) {
            int s = src_p[j];
            float en = enorm_p[j];
            float er = bf2f(ecs[(size_t)j * DD + c])
                     + bf2f(Dh[(size_t)s * DD + c]) + ehv;
            float sg = sigmoidf_(er);
            num += sg * bf2f(Bh[(size_t)s * DD + c]);
            den += sg;
            float es = er * en;
            if (store_es) ecs[(size_t)j * DD + c] = f2bf(es);
            se += es; se2 += es * es;
        }
        float x = (bf2f(Ah[(size_t)n * DD + c]) + num / (den + 1e-6f)) * nnorm[n];
        hraw[(size_t)n * DD + c] = x;
        sh += x; sh2 += x * x;
    }

    red[wid][0][c] = se;  red[wid][1][c] = se2;
    red[wid][2][c] = sh;  red[wid][3][c] = sh2;
    __syncthreads();
    if (threadIdx.x < DD) {
        int t = threadIdx.x;
        float t0 = 0.f, t1 = 0.f, t2 = 0.f, t3 = 0.f;
        #pragma unroll
        for (int w = 0; w < 4; ++w) {
            t0 += red[w][0][t]; t1 += red[w][1][t];
            t2 += red[w][2][t]; t3 += red[w][3][t];
        }
        unsafeAtomicAdd(&stats[t], t0);
        unsafeAtomicAdd(&stats[DD + t], t1);
        unsafeAtomicAdd(&stats[2 * DD + t], t2);
        unsafeAtomicAdd(&stats[3 * DD + t], t3);
    }
}

// ---------------------------------------------------------------------------
__global__ void bn_fin2_v6(const float* __restrict__ stats, float Ecnt, float Ncnt,
                           float* __restrict__ bnp)
{
    int t = threadIdx.x;   // 128 threads
    if (t < DD) {
        float mu  = stats[t] / Ecnt;
        float var = stats[DD + t] / Ecnt - mu * mu;
        bnp[t] = mu;
        bnp[DD + t] = rsqrtf(var + 1e-5f);
    } else {
        int cc = t - DD;
        float mu  = stats[2 * DD + cc] / Ncnt;
        float var = stats[3 * DD + cc] / Ncnt - mu * mu;
        bnp[2 * DD + cc] = mu;
        bnp[3 * DD + cc] = rsqrtf(var + 1e-5f);
    }
}

// ---------------------------------------------------------------------------
// h = h + relu(gamma*(hraw-mu)*istd + beta); h, hraw f32.
// ---------------------------------------------------------------------------
__global__ __launch_bounds__(256) void node_apply_v6(
    const float* __restrict__ hraw, const float* __restrict__ bnph,
    const float* __restrict__ gamma, const float* __restrict__ beta,
    float* __restrict__ h, int N)
{
    int cc = (threadIdx.x & 15) * 4;
    float4 mu = *(const float4*)(bnph + cc);
    float4 is = *(const float4*)(bnph + DD + cc);
    float4 g  = *(const float4*)(gamma + cc);
    float4 b  = *(const float4*)(beta + cc);
    int total = N * 16;
    int stride = gridDim.x * blockDim.x;
    for (int u = blockIdx.x * blockDim.x + threadIdx.x; u < total; u += stride) {
        size_t off = ((size_t)(u >> 4)) * DD + ((u & 15) * 4);
        float4 x   = *(const float4*)(hraw + off);
        float4 hin = *(const float4*)(h + off);
        float4 y;
        y.x = hin.x + fmaxf(g.x * (x.x - mu.x) * is.x + b.x, 0.f);
        y.y = hin.y + fmaxf(g.y * (x.y - mu.y) * is.y + b.y, 0.f);
        y.z = hin.z + fmaxf(g.z * (x.z - mu.z) * is.z + b.z, 0.f);
        y.w = hin.w + fmaxf(g.w * (x.w - mu.w) * is.w + b.w, 0.f);
        *(float4*)(h + off) = y;
    }
}

// ---------------------------------------------------------------------------
__global__ __launch_bounds__(256) void readout_v6(
    const float* __restrict__ h, const int* __restrict__ gid,
    float* __restrict__ hg, float* __restrict__ counts, int N)
{
    int total = N * 16;
    int stride = gridDim.x * blockDim.x;
    for (int u = blockIdx.x * blockDim.x + threadIdx.x; u < total; u += stride) {
        int n = u >> 4;
        int c = (u & 15) * 4;
        int g = gid[n];
        float4 x = *(const float4*)(h + (size_t)n * DD + c);
        float* p = hg + (size_t)g * DD + c;
        unsafeAtomicAdd(p + 0, x.x);
        unsafeAtomicAdd(p + 1, x.y);
        unsafeAtomicAdd(p + 2, x.z);
        unsafeAtomicAdd(p + 3, x.w);
        if ((u & 15) == 0) unsafeAtomicAdd(&counts[g], 1.0f);
    }
}

__global__ void readout_div_v6(const float* __restrict__ hg,
                               const float* __restrict__ counts,
                               float* __restrict__ out, int GD)
{
    int i = blockIdx.x * blockDim.x + threadIdx.x;
    if (i < GD) {
        int g = i >> 6;
        out[i] = hg[i] / fmaxf(counts[g], 1.0f);
    }
}

// ---------------------------------------------------------------------------
extern "C" void kernel_launch(void* const* d_in, const int* in_sizes, int n_in,
                              void* d_out, int out_size, void* d_ws, size_t ws_size,
                              hipStream_t stream)
{
    const float* nodes_feat = (const float*)d_in[0];
    const float* edges_feat = (const float*)d_in[1];
    const float* nnorm      = (const float*)d_in[2];
    const float* enorm      = (const float*)d_in[3];
    const float* W_h = (const float*)d_in[4];
    const float* b_h = (const float*)d_in[5];
    const float* W_e = (const float*)d_in[6];
    const float* b_e = (const float*)d_in[7];
    const float* Wa  = (const float*)d_in[8];
    const float* ba  = (const float*)d_in[9];
    const float* Wb_ = (const float*)d_in[10];
    const float* bb_ = (const float*)d_in[11];
    const float* Wc  = (const float*)d_in[12];
    const float* bc  = (const float*)d_in[13];
    const float* Wd  = (const float*)d_in[14];
    const float* bd  = (const float*)d_in[15];
    const float* We_ = (const float*)d_in[16];
    const float* be_ = (const float*)d_in[17];
    const float* gamma_h = (const float*)d_in[18];
    const float* beta_h  = (const float*)d_in[19];
    const float* gamma_e = (const float*)d_in[20];
    const float* beta_e  = (const float*)d_in[21];
    const int* esrc = (const int*)d_in[22];
    const int* edst = (const int*)d_in[23];
    const int* gid  = (const int*)d_in[24];

    const int N = in_sizes[0] / DIN;
    const int E = in_sizes[1];
    const int G = out_size / DD;
    const int L = in_sizes[8] / (DD * DD);

    // ---- workspace layout (~254.7 MB) ----
    float* f = (float*)d_ws;
    float* h       = f; f += (size_t)N * DD;
    float* hraw    = f; f += (size_t)N * DD;
    float* stats   = f; f += 256;
    float* bnp     = f; f += 256;
    float* hg      = f; f += (size_t)G * DD;   // } zeroed together
    float* gcnt    = f; f += G;                // }
    int*   coffs   = (int*)f; f += (size_t)(N + 2);
    float* enorm_p = f; f += (size_t)E;
    unsigned short* src_p = (unsigned short*)f; f += (size_t)((E + 1) / 2);
    bfu* bp = (bfu*)f;
    bfu* Ah  = bp; bp += (size_t)N * DD;
    bfu* Bh  = bp; bp += (size_t)N * DD;
    bfu* Dh  = bp; bp += (size_t)N * DD;
    bfu* e_p = bp; bp += (size_t)E * DD;
    bfu* ecs = bp; bp += (size_t)E * DD;
    // setup-only CSR scratch overlays the ecs region (dead until layer 0 GEMM)
    int* ccounts = (int*)ecs;
    int* ccursor = ccounts + (N + 1);
    int* cpart   = ccursor + (N + 1);
    int* csr_eid = cpart + 256;

    dim3 blk(256);

    hipMemsetAsync(hg, 0, ((size_t)G * DD + G) * sizeof(float), stream);
    hipMemsetAsync(ccounts, 0, (size_t)(N + 1) * sizeof(int), stream);

    embed_h_v6<<<(N + 31) / 32, blk, 0, stream>>>(nodes_feat, W_h, b_h, h, N);

    const int M  = N + 1;
    const int CH = (M + 255) / 256;
    csr_hist_v6<<<2048, blk, 0, stream>>>(edst, ccounts, E);
    csr_scan_a_v6<<<256, blk, 0, stream>>>(ccounts, cpart, M, CH);
    csr_scan_b_v6<<<1, blk, 0, stream>>>(cpart);
    csr_scan_c_v6<<<256, blk, 0, stream>>>(ccounts, cpart, coffs, ccursor, M, CH);
    csr_scatter_v6<<<2048, blk, 0, stream>>>(edst, ccursor, csr_eid, E);
    perm_build_v6<<<2048, blk, 0, stream>>>(csr_eid, esrc, enorm, src_p, enorm_p, E);
    embed_e_perm_v6<<<2048, blk, 0, stream>>>(edges_feat, W_e, b_e, csr_eid, e_p, E);

    for (int l = 0; l < L; ++l) {
        node_mm3_v6<<<(N + 63) / 64, dim3(192), 0, stream>>>(
            h, Wa + (size_t)l * DD * DD, ba + (size_t)l * DD,
            Wb_ + (size_t)l * DD * DD, bb_ + (size_t)l * DD,
            Wd + (size_t)l * DD * DD, bd + (size_t)l * DD,
            Ah, Bh, Dh, N);
        hipMemsetAsync(stats, 0, 256 * sizeof(float), stream);
        ec_gemm_v6<<<2048, blk, 0, stream>>>(
            e_p, ecs, Wc + (size_t)l * DD * DD, bc + (size_t)l * DD,
            bnp,
            (l > 0) ? gamma_e + (size_t)(l - 1) * DD : gamma_e,
            (l > 0) ? beta_e  + (size_t)(l - 1) * DD : beta_e,
            (l > 0) ? 1 : 0, E);
        fused_accum_v6<<<2048, blk, 0, stream>>>(
            ecs, Ah, Bh, Dh, h,
            We_ + (size_t)l * DD * DD, be_ + (size_t)l * DD,
            coffs, src_p, enorm_p, nnorm, hraw, stats, N,
            (l < L - 1) ? 1 : 0);
        bn_fin2_v6<<<1, 128, 0, stream>>>(stats, (float)E, (float)N, bnp);
        node_apply_v6<<<1024, blk, 0, stream>>>(
            hraw, bnp + 2 * DD,
            gamma_h + (size_t)l * DD, beta_h + (size_t)l * DD, h, N);
    }

    readout_v6<<<1024, blk, 0, stream>>>(h, gid, hg, gcnt, N);
    readout_div_v6<<<(G * DD + 255) / 256, blk, 0, stream>>>(
        hg, gcnt, (float*)d_out, G * DD);
}

// Round 7
// 2496.300 us; speedup vs baseline: 1.3674x; 1.3674x over previous
//
#include <hip/hip_runtime.h>
#include <cstddef>

#define DIN 128
#define DD 64

typedef unsigned short bfu;   // raw bf16 bits

static __device__ __forceinline__ float bf2f(bfu u) {
    union { unsigned int i; float f; } v; v.i = ((unsigned int)u) << 16; return v.f;
}
static __device__ __forceinline__ bfu f2bf(float f) {
    union { float f; unsigned int i; } v; v.f = f;
    unsigned int r = v.i + 0x7FFFu + ((v.i >> 16) & 1u);   // round-nearest-even
    return (bfu)(r >> 16);
}
static __device__ __forceinline__ float4 bf4_to_f4(ushort4 u) {
    return make_float4(bf2f(u.x), bf2f(u.y), bf2f(u.z), bf2f(u.w));
}
static __device__ __forceinline__ ushort4 f4_to_bf4(float4 f) {
    ushort4 u; u.x = f2bf(f.x); u.y = f2bf(f.y); u.z = f2bf(f.z); u.w = f2bf(f.w); return u;
}
static __device__ __forceinline__ float sigmoidf_(float x) {
    return 1.0f / (1.0f + __expf(-x));
}
static __device__ __forceinline__ float readlane_f(float v, int lane) {
    return __uint_as_float(__builtin_amdgcn_readlane(__float_as_uint(v), lane));
}

// ---------------------------------------------------------------------------
// h0 = nodes_feat @ W_h + b_h   [N,128]@[128,64] -> f32
// ---------------------------------------------------------------------------
__global__ __launch_bounds__(256) void embed_h_v7(
    const float* __restrict__ x, const float* __restrict__ Wh,
    const float* __restrict__ bh, float* __restrict__ h, int N)
{
    __shared__ float w[DIN][DD];    // 32 KB
    __shared__ float xs[32][DIN];   // 16 KB
    for (int i = threadIdx.x; i < DIN * DD / 4; i += 256)
        ((float4*)w)[i] = ((const float4*)Wh)[i];
    int row0 = blockIdx.x * 32;
    for (int i = threadIdx.x; i < 32 * DIN / 4; i += 256) {
        int r = i >> 5, k = (i & 31) * 4;
        int row = row0 + r;
        float4 v = make_float4(0.f, 0.f, 0.f, 0.f);
        if (row < N) v = *(const float4*)(x + (size_t)row * DIN + k);
        *(float4*)(&xs[r][k]) = v;
    }
    __syncthreads();
    int rl = threadIdx.x >> 6;
    int c  = threadIdx.x & 63;
    float b = bh[c];
    for (int rr = 0; rr < 8; ++rr) {
        int r = rl * 8 + rr;
        int row = row0 + r;
        if (row >= N) break;
        float acc = b;
        #pragma unroll
        for (int k = 0; k < DIN; k += 4) {
            float4 xv = *(const float4*)(&xs[r][k]);
            acc += xv.x * w[k][c] + xv.y * w[k+1][c] + xv.z * w[k+2][c] + xv.w * w[k+3][c];
        }
        h[(size_t)row * DD + c] = acc;
    }
}

// ---------------------------------------------------------------------------
// CSR build (by dst): histogram -> 3-phase exclusive scan -> scatter
// ---------------------------------------------------------------------------
__global__ void csr_hist_v7(const int* __restrict__ dst, int* __restrict__ counts, int E)
{
    for (int i = blockIdx.x * blockDim.x + threadIdx.x; i < E; i += gridDim.x * blockDim.x)
        atomicAdd(&counts[dst[i]], 1);
}

__global__ void csr_scan_a_v7(const int* __restrict__ counts, int* __restrict__ part,
                              int M, int CH)
{
    __shared__ int sd[256];
    int b = blockIdx.x, t = threadIdx.x;
    int idx = b * CH + t;
    int v = (t < CH && idx < M) ? counts[idx] : 0;
    sd[t] = v; __syncthreads();
    for (int off = 128; off > 0; off >>= 1) {
        if (t < off) sd[t] += sd[t + off];
        __syncthreads();
    }
    if (t == 0) part[b] = sd[0];
}

__global__ void csr_scan_b_v7(int* __restrict__ part)
{
    __shared__ int sd[256];
    int t = threadIdx.x;
    int v = part[t];
    sd[t] = v; __syncthreads();
    for (int off = 1; off < 256; off <<= 1) {
        int u = (t >= off) ? sd[t - off] : 0;
        __syncthreads();
        sd[t] += u;
        __syncthreads();
    }
    part[t] = sd[t] - v;   // exclusive
}

__global__ void csr_scan_c_v7(const int* __restrict__ counts, const int* __restrict__ part,
                              int* __restrict__ offsets, int* __restrict__ cursor,
                              int M, int CH)
{
    __shared__ int sd[256];
    int b = blockIdx.x, t = threadIdx.x;
    int idx = b * CH + t;
    int v = (t < CH && idx < M) ? counts[idx] : 0;
    sd[t] = v; __syncthreads();
    for (int off = 1; off < 256; off <<= 1) {
        int u = (t >= off) ? sd[t - off] : 0;
        __syncthreads();
        sd[t] += u;
        __syncthreads();
    }
    int excl = sd[t] - v + part[b];
    if (t < CH && idx < M) { offsets[idx] = excl; cursor[idx] = excl; }
}

__global__ void csr_scatter_v7(const int* __restrict__ dst, int* __restrict__ cursor,
                               int* __restrict__ csr_eid, int E)
{
    for (int i = blockIdx.x * blockDim.x + threadIdx.x; i < E; i += gridDim.x * blockDim.x) {
        int p = atomicAdd(&cursor[dst[i]], 1);
        csr_eid[p] = i;
    }
}

// src_p[j] = (ushort)esrc[csr_eid[j]]; enorm_p[j] = enorm[csr_eid[j]]
__global__ void perm_build_v7(const int* __restrict__ csr_eid, const int* __restrict__ esrc,
                              const float* __restrict__ enorm,
                              unsigned short* __restrict__ src_p,
                              float* __restrict__ enorm_p, int E)
{
    for (int i = blockIdx.x * blockDim.x + threadIdx.x; i < E; i += gridDim.x * blockDim.x) {
        int eid = csr_eid[i];
        src_p[i] = (unsigned short)esrc[eid];
        enorm_p[i] = enorm[eid];
    }
}

// e_p[j] = bf16(edges_feat[csr_eid[j]] * W_e + b_e)
__global__ __launch_bounds__(256) void embed_e_perm_v7(
    const float* __restrict__ ef, const float* __restrict__ We,
    const float* __restrict__ be, const int* __restrict__ csr_eid,
    bfu* __restrict__ e, int E)
{
    int c = (threadIdx.x & 15) * 4;
    float4 w = *(const float4*)(We + c);
    float4 b = *(const float4*)(be + c);
    int total = E * 16;
    int stride = gridDim.x * blockDim.x;
    for (int u = blockIdx.x * blockDim.x + threadIdx.x; u < total; u += stride) {
        int j = u >> 4;
        float f = ef[csr_eid[j]];
        float4 o;
        o.x = f * w.x + b.x; o.y = f * w.y + b.y;
        o.z = f * w.z + b.z; o.w = f * w.w + b.w;
        *(ushort4*)(e + (size_t)j * DD + c) = f4_to_bf4(o);
    }
}

// ---------------------------------------------------------------------------
// Ah/Bh/Dh = h @ W{a,b,d} + bias.  192 threads: one wave per matrix.
// ---------------------------------------------------------------------------
__global__ __launch_bounds__(192) void node_mm3_v7(
    const float* __restrict__ h,
    const float* __restrict__ Wa, const float* __restrict__ ba,
    const float* __restrict__ Wb, const float* __restrict__ bbv,
    const float* __restrict__ Wd, const float* __restrict__ bd,
    bfu* __restrict__ Ah, bfu* __restrict__ Bh, bfu* __restrict__ Dh, int N)
{
    __shared__ float hs[64][DD];   // 16 KB
    int row0 = blockIdx.x * 64;
    for (int i = threadIdx.x; i < 64 * 16; i += 192) {
        int r = i >> 4, cc = (i & 15) * 4;
        int row = row0 + r;
        float4 v = make_float4(0.f, 0.f, 0.f, 0.f);
        if (row < N) v = *(const float4*)(h + (size_t)row * DD + cc);
        *(float4*)(&hs[r][cc]) = v;
    }
    __syncthreads();
    int m = threadIdx.x / 64;
    int c = threadIdx.x & 63;
    const float* W    = (m == 0) ? Wa : (m == 1) ? Wb : Wd;
    const float* bias = (m == 0) ? ba : (m == 1) ? bbv : bd;
    bfu*         Out  = (m == 0) ? Ah : (m == 1) ? Bh : Dh;
    float wcol[DD];
    #pragma unroll
    for (int k = 0; k < DD; ++k) wcol[k] = W[k * DD + c];
    float b = bias[c];
    int rmax = (N - row0 < 64) ? (N - row0) : 64;
    for (int r = 0; r < rmax; ++r) {
        float acc = b;
        #pragma unroll
        for (int k = 0; k < DD; k += 4) {
            float4 hv = *(const float4*)(&hs[r][k]);
            acc += hv.x * wcol[k] + hv.y * wcol[k+1] + hv.z * wcol[k+2] + hv.w * wcol[k+3];
        }
        Out[(size_t)(row0 + r) * DD + c] = f2bf(acc);
    }
}

// ---------------------------------------------------------------------------
// ec_gemm v7: per 64-edge chunk:
//   stage (16 rows x 16 col-groups per pass): [optional fused BN-apply of
//   PREVIOUS layer: e_new = e_old + relu(g*(es-mu)*istd+bt), es read from
//   ecs, e_new written back to e unless last layer] -> els (f32, LDS)
//   GEMM: thread = output channel c (Wc column in 64 REGISTERS), wave w
//   handles rows w*16..w*16+15; els row reads are wave-broadcast b128.
//   Output ecs[j*64+c] bf16 (contiguous 128B per wave store).
// ---------------------------------------------------------------------------
__global__ __launch_bounds__(256) void ec_gemm_v7(
    bfu* __restrict__ e, bfu* __restrict__ ecs,
    const float* __restrict__ Wc, const float* __restrict__ bc,
    const float* __restrict__ bnp, const float* __restrict__ gamma,
    const float* __restrict__ beta, int apply, int store_e, int E)
{
    __shared__ float els[64][DD];   // 16 KB
    int c = threadIdx.x & 63;       // GEMM output channel
    int w = threadIdx.x >> 6;       // wave id 0..3
    float wcol[DD];
    #pragma unroll
    for (int k = 0; k < DD; ++k) wcol[k] = Wc[k * DD + c];
    float bcc = bc[c];

    int sr = threadIdx.x >> 4;          // staging row 0..15
    int sc = (threadIdx.x & 15) * 4;    // staging channel group
    float4 mu = make_float4(0,0,0,0), isd = mu, g4 = mu, bt = mu;
    if (apply) {
        mu  = *(const float4*)(bnp + sc);
        isd = *(const float4*)(bnp + DD + sc);
        g4  = *(const float4*)(gamma + sc);
        bt  = *(const float4*)(beta + sc);
    }

    int stride = gridDim.x * 64;
    for (int base = blockIdx.x * 64; base < E; base += stride) {
        __syncthreads();
        #pragma unroll
        for (int rr = 0; rr < 4; ++rr) {
            int r = rr * 16 + sr;
            int j = base + r;
            float4 v = make_float4(0.f, 0.f, 0.f, 0.f);
            if (j < E) {
                size_t off = (size_t)j * DD + sc;
                v = bf4_to_f4(*(const ushort4*)(e + off));
                if (apply) {
                    float4 es4 = bf4_to_f4(*(const ushort4*)(ecs + off));
                    v.x += fmaxf(g4.x * (es4.x - mu.x) * isd.x + bt.x, 0.f);
                    v.y += fmaxf(g4.y * (es4.y - mu.y) * isd.y + bt.y, 0.f);
                    v.z += fmaxf(g4.z * (es4.z - mu.z) * isd.z + bt.z, 0.f);
                    v.w += fmaxf(g4.w * (es4.w - mu.w) * isd.w + bt.w, 0.f);
                    if (store_e) *(ushort4*)(e + off) = f4_to_bf4(v);
                }
            }
            *(float4*)(&els[r][sc]) = v;
        }
        __syncthreads();
        // GEMM phase: wave-broadcast row reads, register weight column
        int rmax = E - base;
        if (rmax > 16) rmax = 16;
        int rlim = (E - base >= 64) ? 16 : ((E - base > w * 16) ? (E - base - w * 16) : 0);
        if (rlim > 16) rlim = 16;
        for (int rr = 0; rr < rlim; ++rr) {
            int r = w * 16 + rr;
            float acc = bcc;
            #pragma unroll
            for (int k = 0; k < DD; k += 4) {
                float4 ev = *(const float4*)(&els[r][k]);
                acc += ev.x*wcol[k] + ev.y*wcol[k+1] + ev.z*wcol[k+2] + ev.w*wcol[k+3];
            }
            ecs[(size_t)(base + r) * DD + c] = f2bf(acc);
        }
    }
}

// ---------------------------------------------------------------------------
// fused node-centric accumulation: one WAVE per dst node, lane = channel.
// Eh[n] computed on the fly (readlane matvec over f32 h row); per edge j:
// er = ecs[j] + Dh[src] + Eh; num/den in registers; es = er*enorm written
// back into ecs (in place) for the next layer's fused BN-apply.
// stats: [0:64) sum es | [64:128) es^2 | [128:192) x | [192:256) x^2
// ---------------------------------------------------------------------------
__global__ __launch_bounds__(256) void fused_accum_v7(
    bfu* __restrict__ ecs,
    const bfu* __restrict__ Ah, const bfu* __restrict__ Bh, const bfu* __restrict__ Dh,
    const float* __restrict__ h, const float* __restrict__ We, const float* __restrict__ be,
    const int* __restrict__ coffs, const unsigned short* __restrict__ src_p,
    const float* __restrict__ enorm_p, const float* __restrict__ nnorm,
    float* __restrict__ hraw, float* __restrict__ stats, int N, int store_es)
{
    __shared__ float red[4][4][DD];
    int wid = threadIdx.x >> 6;
    int c   = threadIdx.x & 63;
    float wcol[DD];
    #pragma unroll
    for (int k = 0; k < DD; ++k) wcol[k] = We[k * DD + c];
    float bec = be[c];
    float se = 0.f, se2 = 0.f, sh = 0.f, sh2 = 0.f;

    int gw = blockIdx.x * 4 + wid;
    int gstride = gridDim.x * 4;
    for (int n = gw; n < N; n += gstride) {
        int j0 = coffs[n], j1 = coffs[n + 1];
        float hv = h[(size_t)n * DD + c];
        float e0 = bec, e1 = 0.f, e2 = 0.f, e3 = 0.f;
        #pragma unroll
        for (int k = 0; k < DD; k += 4) {
            e0 += readlane_f(hv, k)     * wcol[k];
            e1 += readlane_f(hv, k + 1) * wcol[k + 1];
            e2 += readlane_f(hv, k + 2) * wcol[k + 2];
            e3 += readlane_f(hv, k + 3) * wcol[k + 3];
        }
        float ehv = (e0 + e1) + (e2 + e3);
        float num = 0.f, den = 0.f;
        for (int j = j0; j < j1; ++j) {
            int s = src_p[j];
            float en = enorm_p[j];
            float er = bf2f(ecs[(size_t)j * DD + c])
                     + bf2f(Dh[(size_t)s * DD + c]) + ehv;
            float sg = sigmoidf_(er);
            num += sg * bf2f(Bh[(size_t)s * DD + c]);
            den += sg;
            float es = er * en;
            if (store_es) ecs[(size_t)j * DD + c] = f2bf(es);
            se += es; se2 += es * es;
        }
        float x = (bf2f(Ah[(size_t)n * DD + c]) + num / (den + 1e-6f)) * nnorm[n];
        hraw[(size_t)n * DD + c] = x;
        sh += x; sh2 += x * x;
    }

    red[wid][0][c] = se;  red[wid][1][c] = se2;
    red[wid][2][c] = sh;  red[wid][3][c] = sh2;
    __syncthreads();
    if (threadIdx.x < DD) {
        int t = threadIdx.x;
        float t0 = 0.f, t1 = 0.f, t2 = 0.f, t3 = 0.f;
        #pragma unroll
        for (int w = 0; w < 4; ++w) {
            t0 += red[w][0][t]; t1 += red[w][1][t];
            t2 += red[w][2][t]; t3 += red[w][3][t];
        }
        unsafeAtomicAdd(&stats[t], t0);
        unsafeAtomicAdd(&stats[DD + t], t1);
        unsafeAtomicAdd(&stats[2 * DD + t], t2);
        unsafeAtomicAdd(&stats[3 * DD + t], t3);
    }
}

// ---------------------------------------------------------------------------
__global__ void bn_fin2_v7(const float* __restrict__ stats, float Ecnt, float Ncnt,
                           float* __restrict__ bnp)
{
    int t = threadIdx.x;   // 128 threads
    if (t < DD) {
        float mu  = stats[t] / Ecnt;
        float var = stats[DD + t] / Ecnt - mu * mu;
        bnp[t] = mu;
        bnp[DD + t] = rsqrtf(var + 1e-5f);
    } else {
        int cc = t - DD;
        float mu  = stats[2 * DD + cc] / Ncnt;
        float var = stats[3 * DD + cc] / Ncnt - mu * mu;
        bnp[2 * DD + cc] = mu;
        bnp[3 * DD + cc] = rsqrtf(var + 1e-5f);
    }
}

// ---------------------------------------------------------------------------
// h = h + relu(gamma*(hraw-mu)*istd + beta); h, hraw f32.
// ---------------------------------------------------------------------------
__global__ __launch_bounds__(256) void node_apply_v7(
    const float* __restrict__ hraw, const float* __restrict__ bnph,
    const float* __restrict__ gamma, const float* __restrict__ beta,
    float* __restrict__ h, int N)
{
    int cc = (threadIdx.x & 15) * 4;
    float4 mu = *(const float4*)(bnph + cc);
    float4 is = *(const float4*)(bnph + DD + cc);
    float4 g  = *(const float4*)(gamma + cc);
    float4 b  = *(const float4*)(beta + cc);
    int total = N * 16;
    int stride = gridDim.x * blockDim.x;
    for (int u = blockIdx.x * blockDim.x + threadIdx.x; u < total; u += stride) {
        size_t off = ((size_t)(u >> 4)) * DD + ((u & 15) * 4);
        float4 x   = *(const float4*)(hraw + off);
        float4 hin = *(const float4*)(h + off);
        float4 y;
        y.x = hin.x + fmaxf(g.x * (x.x - mu.x) * is.x + b.x, 0.f);
        y.y = hin.y + fmaxf(g.y * (x.y - mu.y) * is.y + b.y, 0.f);
        y.z = hin.z + fmaxf(g.z * (x.z - mu.z) * is.z + b.z, 0.f);
        y.w = hin.w + fmaxf(g.w * (x.w - mu.w) * is.w + b.w, 0.f);
        *(float4*)(h + off) = y;
    }
}

// ---------------------------------------------------------------------------
__global__ __launch_bounds__(256) void readout_v7(
    const float* __restrict__ h, const int* __restrict__ gid,
    float* __restrict__ hg, float* __restrict__ counts, int N)
{
    int total = N * 16;
    int stride = gridDim.x * blockDim.x;
    for (int u = blockIdx.x * blockDim.x + threadIdx.x; u < total; u += stride) {
        int n = u >> 4;
        int c = (u & 15) * 4;
        int g = gid[n];
        float4 x = *(const float4*)(h + (size_t)n * DD + c);
        float* p = hg + (size_t)g * DD + c;
        unsafeAtomicAdd(p + 0, x.x);
        unsafeAtomicAdd(p + 1, x.y);
        unsafeAtomicAdd(p + 2, x.z);
        unsafeAtomicAdd(p + 3, x.w);
        if ((u & 15) == 0) unsafeAtomicAdd(&counts[g], 1.0f);
    }
}

__global__ void readout_div_v7(const float* __restrict__ hg,
                               const float* __restrict__ counts,
                               float* __restrict__ out, int GD)
{
    int i = blockIdx.x * blockDim.x + threadIdx.x;
    if (i < GD) {
        int g = i >> 6;
        out[i] = hg[i] / fmaxf(counts[g], 1.0f);
    }
}

// ---------------------------------------------------------------------------
extern "C" void kernel_launch(void* const* d_in, const int* in_sizes, int n_in,
                              void* d_out, int out_size, void* d_ws, size_t ws_size,
                              hipStream_t stream)
{
    const float* nodes_feat = (const float*)d_in[0];
    const float* edges_feat = (const float*)d_in[1];
    const float* nnorm      = (const float*)d_in[2];
    const float* enorm      = (const float*)d_in[3];
    const float* W_h = (const float*)d_in[4];
    const float* b_h = (const float*)d_in[5];
    const float* W_e = (const float*)d_in[6];
    const float* b_e = (const float*)d_in[7];
    const float* Wa  = (const float*)d_in[8];
    const float* ba  = (const float*)d_in[9];
    const float* Wb_ = (const float*)d_in[10];
    const float* bb_ = (const float*)d_in[11];
    const float* Wc  = (const float*)d_in[12];
    const float* bc  = (const float*)d_in[13];
    const float* Wd  = (const float*)d_in[14];
    const float* bd  = (const float*)d_in[15];
    const float* We_ = (const float*)d_in[16];
    const float* be_ = (const float*)d_in[17];
    const float* gamma_h = (const float*)d_in[18];
    const float* beta_h  = (const float*)d_in[19];
    const float* gamma_e = (const float*)d_in[20];
    const float* beta_e  = (const float*)d_in[21];
    const int* esrc = (const int*)d_in[22];
    const int* edst = (const int*)d_in[23];
    const int* gid  = (const int*)d_in[24];

    const int N = in_sizes[0] / DIN;
    const int E = in_sizes[1];
    const int G = out_size / DD;
    const int L = in_sizes[8] / (DD * DD);

    // ---- workspace layout (~254.7 MB) ----
    float* f = (float*)d_ws;
    float* h       = f; f += (size_t)N * DD;
    float* hraw    = f; f += (size_t)N * DD;
    float* stats   = f; f += 256;
    float* bnp     = f; f += 256;
    float* hg      = f; f += (size_t)G * DD;   // } zeroed together
    float* gcnt    = f; f += G;                // }
    int*   coffs   = (int*)f; f += (size_t)(N + 2);
    float* enorm_p = f; f += (size_t)E;
    unsigned short* src_p = (unsigned short*)f; f += (size_t)((E + 1) / 2);
    bfu* bp = (bfu*)f;
    bfu* Ah  = bp; bp += (size_t)N * DD;
    bfu* Bh  = bp; bp += (size_t)N * DD;
    bfu* Dh  = bp; bp += (size_t)N * DD;
    bfu* e_p = bp; bp += (size_t)E * DD;
    bfu* ecs = bp; bp += (size_t)E * DD;
    // setup-only CSR scratch overlays the ecs region (dead until layer 0 GEMM)
    int* ccounts = (int*)ecs;
    int* ccursor = ccounts + (N + 1);
    int* cpart   = ccursor + (N + 1);
    int* csr_eid = cpart + 256;

    dim3 blk(256);

    hipMemsetAsync(hg, 0, ((size_t)G * DD + G) * sizeof(float), stream);
    hipMemsetAsync(ccounts, 0, (size_t)(N + 1) * sizeof(int), stream);

    embed_h_v7<<<(N + 31) / 32, blk, 0, stream>>>(nodes_feat, W_h, b_h, h, N);

    const int M  = N + 1;
    const int CH = (M + 255) / 256;
    csr_hist_v7<<<2048, blk, 0, stream>>>(edst, ccounts, E);
    csr_scan_a_v7<<<256, blk, 0, stream>>>(ccounts, cpart, M, CH);
    csr_scan_b_v7<<<1, blk, 0, stream>>>(cpart);
    csr_scan_c_v7<<<256, blk, 0, stream>>>(ccounts, cpart, coffs, ccursor, M, CH);
    csr_scatter_v7<<<2048, blk, 0, stream>>>(edst, ccursor, csr_eid, E);
    perm_build_v7<<<2048, blk, 0, stream>>>(csr_eid, esrc, enorm, src_p, enorm_p, E);
    embed_e_perm_v7<<<2048, blk, 0, stream>>>(edges_feat, W_e, b_e, csr_eid, e_p, E);

    for (int l = 0; l < L; ++l) {
        node_mm3_v7<<<(N + 63) / 64, dim3(192), 0, stream>>>(
            h, Wa + (size_t)l * DD * DD, ba + (size_t)l * DD,
            Wb_ + (size_t)l * DD * DD, bb_ + (size_t)l * DD,
            Wd + (size_t)l * DD * DD, bd + (size_t)l * DD,
            Ah, Bh, Dh, N);
        hipMemsetAsync(stats, 0, 256 * sizeof(float), stream);
        ec_gemm_v7<<<2048, blk, 0, stream>>>(
            e_p, ecs, Wc + (size_t)l * DD * DD, bc + (size_t)l * DD,
            bnp,
            (l > 0) ? gamma_e + (size_t)(l - 1) * DD : gamma_e,
            (l > 0) ? beta_e  + (size_t)(l - 1) * DD : beta_e,
            (l > 0) ? 1 : 0,
            (l < L - 1) ? 1 : 0, E);
        fused_accum_v7<<<2048, blk, 0, stream>>>(
            ecs, Ah, Bh, Dh, h,
            We_ + (size_t)l * DD * DD, be_ + (size_t)l * DD,
            coffs, src_p, enorm_p, nnorm, hraw, stats, N,
            (l < L - 1) ? 1 : 0);
        bn_fin2_v7<<<1, 128, 0, stream>>>(stats, (float)E, (float)N, bnp);
        node_apply_v7<<<1024, blk, 0, stream>>>(
            hraw, bnp + 2 * DD,
            gamma_h + (size_t)l * DD, beta_h + (size_t)l * DD, h, N);
    }

    readout_v7<<<1024, blk, 0, stream>>>(h, gid, hg, gcnt, N);
    readout_div_v7<<<(G * DD + 255) / 256, blk, 0, stream>>>(
        hg, gcnt, (float*)d_out, G * DD);
}

// Round 8
// 1553.695 us; speedup vs baseline: 2.1970x; 1.6067x over previous
//
#include <hip/hip_runtime.h>
#include <cstddef>

#define DIN 128
#define DD 64

typedef unsigned short bfu;   // raw bf16 bits
typedef __attribute__((ext_vector_type(8))) short bf16x8;
typedef __attribute__((ext_vector_type(4))) float f32x4;

static __device__ __forceinline__ float bf2f(bfu u) {
    union { unsigned int i; float f; } v; v.i = ((unsigned int)u) << 16; return v.f;
}
static __device__ __forceinline__ bfu f2bf(float f) {
    union { float f; unsigned int i; } v; v.f = f;
    unsigned int r = v.i + 0x7FFFu + ((v.i >> 16) & 1u);   // round-nearest-even
    return (bfu)(r >> 16);
}
static __device__ __forceinline__ float4 bf4_to_f4(ushort4 u) {
    return make_float4(bf2f(u.x), bf2f(u.y), bf2f(u.z), bf2f(u.w));
}
static __device__ __forceinline__ ushort4 f4_to_bf4(float4 f) {
    ushort4 u; u.x = f2bf(f.x); u.y = f2bf(f.y); u.z = f2bf(f.z); u.w = f2bf(f.w); return u;
}
static __device__ __forceinline__ float sigmoidf_(float x) {
    return 1.0f / (1.0f + __expf(-x));
}
static __device__ __forceinline__ float readlane_f(float v, int lane) {
    return __uint_as_float(__builtin_amdgcn_readlane(__float_as_uint(v), lane));
}

// ---------------------------------------------------------------------------
// h0 = nodes_feat @ W_h + b_h   [N,128]@[128,64] -> f32
// ---------------------------------------------------------------------------
__global__ __launch_bounds__(256) void embed_h_v8(
    const float* __restrict__ x, const float* __restrict__ Wh,
    const float* __restrict__ bh, float* __restrict__ h, int N)
{
    __shared__ float w[DIN][DD];    // 32 KB
    __shared__ float xs[32][DIN];   // 16 KB
    for (int i = threadIdx.x; i < DIN * DD / 4; i += 256)
        ((float4*)w)[i] = ((const float4*)Wh)[i];
    int row0 = blockIdx.x * 32;
    for (int i = threadIdx.x; i < 32 * DIN / 4; i += 256) {
        int r = i >> 5, k = (i & 31) * 4;
        int row = row0 + r;
        float4 v = make_float4(0.f, 0.f, 0.f, 0.f);
        if (row < N) v = *(const float4*)(x + (size_t)row * DIN + k);
        *(float4*)(&xs[r][k]) = v;
    }
    __syncthreads();
    int rl = threadIdx.x >> 6;
    int c  = threadIdx.x & 63;
    float b = bh[c];
    for (int rr = 0; rr < 8; ++rr) {
        int r = rl * 8 + rr;
        int row = row0 + r;
        if (row >= N) break;
        float acc = b;
        #pragma unroll
        for (int k = 0; k < DIN; k += 4) {
            float4 xv = *(const float4*)(&xs[r][k]);
            acc += xv.x * w[k][c] + xv.y * w[k+1][c] + xv.z * w[k+2][c] + xv.w * w[k+3][c];
        }
        h[(size_t)row * DD + c] = acc;
    }
}

// ---------------------------------------------------------------------------
// CSR build (by dst): histogram -> 3-phase exclusive scan -> scatter
// ---------------------------------------------------------------------------
__global__ void csr_hist_v8(const int* __restrict__ dst, int* __restrict__ counts, int E)
{
    for (int i = blockIdx.x * blockDim.x + threadIdx.x; i < E; i += gridDim.x * blockDim.x)
        atomicAdd(&counts[dst[i]], 1);
}

__global__ void csr_scan_a_v8(const int* __restrict__ counts, int* __restrict__ part,
                              int M, int CH)
{
    __shared__ int sd[256];
    int b = blockIdx.x, t = threadIdx.x;
    int idx = b * CH + t;
    int v = (t < CH && idx < M) ? counts[idx] : 0;
    sd[t] = v; __syncthreads();
    for (int off = 128; off > 0; off >>= 1) {
        if (t < off) sd[t] += sd[t + off];
        __syncthreads();
    }
    if (t == 0) part[b] = sd[0];
}

__global__ void csr_scan_b_v8(int* __restrict__ part)
{
    __shared__ int sd[256];
    int t = threadIdx.x;
    int v = part[t];
    sd[t] = v; __syncthreads();
    for (int off = 1; off < 256; off <<= 1) {
        int u = (t >= off) ? sd[t - off] : 0;
        __syncthreads();
        sd[t] += u;
        __syncthreads();
    }
    part[t] = sd[t] - v;   // exclusive
}

__global__ void csr_scan_c_v8(const int* __restrict__ counts, const int* __restrict__ part,
                              int* __restrict__ offsets, int* __restrict__ cursor,
                              int M, int CH)
{
    __shared__ int sd[256];
    int b = blockIdx.x, t = threadIdx.x;
    int idx = b * CH + t;
    int v = (t < CH && idx < M) ? counts[idx] : 0;
    sd[t] = v; __syncthreads();
    for (int off = 1; off < 256; off <<= 1) {
        int u = (t >= off) ? sd[t - off] : 0;
        __syncthreads();
        sd[t] += u;
        __syncthreads();
    }
    int excl = sd[t] - v + part[b];
    if (t < CH && idx < M) { offsets[idx] = excl; cursor[idx] = excl; }
}

__global__ void csr_scatter_v8(const int* __restrict__ dst, int* __restrict__ cursor,
                               int* __restrict__ csr_eid, int E)
{
    for (int i = blockIdx.x * blockDim.x + threadIdx.x; i < E; i += gridDim.x * blockDim.x) {
        int p = atomicAdd(&cursor[dst[i]], 1);
        csr_eid[p] = i;
    }
}

__global__ void perm_build_v8(const int* __restrict__ csr_eid, const int* __restrict__ esrc,
                              const float* __restrict__ enorm,
                              unsigned short* __restrict__ src_p,
                              float* __restrict__ enorm_p, int E)
{
    for (int i = blockIdx.x * blockDim.x + threadIdx.x; i < E; i += gridDim.x * blockDim.x) {
        int eid = csr_eid[i];
        src_p[i] = (unsigned short)esrc[eid];
        enorm_p[i] = enorm[eid];
    }
}

__global__ __launch_bounds__(256) void embed_e_perm_v8(
    const float* __restrict__ ef, const float* __restrict__ We,
    const float* __restrict__ be, const int* __restrict__ csr_eid,
    bfu* __restrict__ e, int E)
{
    int c = (threadIdx.x & 15) * 4;
    float4 w = *(const float4*)(We + c);
    float4 b = *(const float4*)(be + c);
    int total = E * 16;
    int stride = gridDim.x * blockDim.x;
    for (int u = blockIdx.x * blockDim.x + threadIdx.x; u < total; u += stride) {
        int j = u >> 4;
        float f = ef[csr_eid[j]];
        float4 o;
        o.x = f * w.x + b.x; o.y = f * w.y + b.y;
        o.z = f * w.z + b.z; o.w = f * w.w + b.w;
        *(ushort4*)(e + (size_t)j * DD + c) = f4_to_bf4(o);
    }
}

// ---------------------------------------------------------------------------
// Ah / DBh = h @ W{a,b,d} + bias.  192 threads: one wave per matrix.
// DBh layout: row n has 128 shorts: [2c]=Dh, [2c+1]=Bh  (one gather in accum)
// ---------------------------------------------------------------------------
__global__ __launch_bounds__(192) void node_mm3_v8(
    const float* __restrict__ h,
    const float* __restrict__ Wa, const float* __restrict__ ba,
    const float* __restrict__ Wb, const float* __restrict__ bbv,
    const float* __restrict__ Wd, const float* __restrict__ bd,
    bfu* __restrict__ Ah, bfu* __restrict__ DBh, int N)
{
    __shared__ float hs[64][DD];   // 16 KB
    int row0 = blockIdx.x * 64;
    for (int i = threadIdx.x; i < 64 * 16; i += 192) {
        int r = i >> 4, cc = (i & 15) * 4;
        int row = row0 + r;
        float4 v = make_float4(0.f, 0.f, 0.f, 0.f);
        if (row < N) v = *(const float4*)(h + (size_t)row * DD + cc);
        *(float4*)(&hs[r][cc]) = v;
    }
    __syncthreads();
    int m = threadIdx.x / 64;
    int c = threadIdx.x & 63;
    const float* W    = (m == 0) ? Wa : (m == 1) ? Wb : Wd;
    const float* bias = (m == 0) ? ba : (m == 1) ? bbv : bd;
    float wcol[DD];
    #pragma unroll
    for (int k = 0; k < DD; ++k) wcol[k] = W[k * DD + c];
    float b = bias[c];
    int rmax = (N - row0 < 64) ? (N - row0) : 64;
    for (int r = 0; r < rmax; ++r) {
        float acc = b;
        #pragma unroll
        for (int k = 0; k < DD; k += 4) {
            float4 hv = *(const float4*)(&hs[r][k]);
            acc += hv.x * wcol[k] + hv.y * wcol[k+1] + hv.z * wcol[k+2] + hv.w * wcol[k+3];
        }
        bfu o = f2bf(acc);
        size_t row = (size_t)(row0 + r);
        if (m == 0)      Ah[row * DD + c] = o;
        else if (m == 1) DBh[row * 128 + 2 * c + 1] = o;   // B
        else             DBh[row * 128 + 2 * c] = o;       // D
    }
}

// ---------------------------------------------------------------------------
// ec_gemm v8 (MFMA): per 64-edge chunk:
//   stage: [fused BN-apply of PREVIOUS layer (es from ecs): e_new =
//   e_old + relu(g*(es-mu)*istd+bt) -> e (unless last layer)] -> els bf16
//   (row stride 72 shorts = 144B, 16B-aligned for ds_read_b128)
//   MFMA: wave w owns rows w*16..w*16+15; A-frag lane l = row l&15,
//   k = 8*(l>>4)+j; B-frags (Wc bf16) in registers; C/D: col=l&15,
//   row=4*(l>>4)+reg.  ecs[j*64+c] = bf16(acc + bc[c]).
// ---------------------------------------------------------------------------
__global__ __launch_bounds__(256) void ec_gemm_v8(
    bfu* __restrict__ e, bfu* __restrict__ ecs,
    const float* __restrict__ Wc, const float* __restrict__ bc,
    const float* __restrict__ bnp, const float* __restrict__ gamma,
    const float* __restrict__ beta, int apply, int store_e, int E)
{
    __shared__ bfu els[64 * 72];   // 9216 B
    int l  = threadIdx.x & 63;
    int w  = threadIdx.x >> 6;
    int lr = l & 15;
    int ld = l >> 4;

    // B fragments: bfrag[ct][kh][j] = Wc[kh*32+8*ld+j][ct*16+lr] (bf16)
    bf16x8 bfrag[4][2];
    #pragma unroll
    for (int ct = 0; ct < 4; ++ct)
        #pragma unroll
        for (int kh = 0; kh < 2; ++kh)
            #pragma unroll
            for (int j = 0; j < 8; ++j)
                bfrag[ct][kh][j] = (short)f2bf(Wc[(kh * 32 + 8 * ld + j) * DD + ct * 16 + lr]);

    float bcl[4];
    #pragma unroll
    for (int ct = 0; ct < 4; ++ct) bcl[ct] = bc[ct * 16 + lr];

    // staging ids
    int sr  = threadIdx.x >> 4;       // 0..15
    int scg = threadIdx.x & 15;       // col group (channels scg*4..+3)
    float4 mu = make_float4(0,0,0,0), isd = mu, g4 = mu, bt = mu;
    if (apply) {
        mu  = *(const float4*)(bnp + scg * 4);
        isd = *(const float4*)(bnp + DD + scg * 4);
        g4  = *(const float4*)(gamma + scg * 4);
        bt  = *(const float4*)(beta + scg * 4);
    }

    int stride = gridDim.x * 64;
    for (int base = blockIdx.x * 64; base < E; base += stride) {
        __syncthreads();
        #pragma unroll
        for (int rr = 0; rr < 4; ++rr) {
            int r = rr * 16 + sr;
            int j = base + r;
            if (j < E) {
                size_t off = (size_t)j * DD + scg * 4;
                ushort4 raw = *(const ushort4*)(e + off);
                if (apply) {
                    float4 v = bf4_to_f4(raw);
                    float4 es4 = bf4_to_f4(*(const ushort4*)(ecs + off));
                    v.x += fmaxf(g4.x * (es4.x - mu.x) * isd.x + bt.x, 0.f);
                    v.y += fmaxf(g4.y * (es4.y - mu.y) * isd.y + bt.y, 0.f);
                    v.z += fmaxf(g4.z * (es4.z - mu.z) * isd.z + bt.z, 0.f);
                    v.w += fmaxf(g4.w * (es4.w - mu.w) * isd.w + bt.w, 0.f);
                    ushort4 nb = f4_to_bf4(v);
                    if (store_e) *(ushort4*)(e + off) = nb;
                    *(ushort4*)(&els[r * 72 + scg * 4]) = nb;
                } else {
                    *(ushort4*)(&els[r * 72 + scg * 4]) = raw;
                }
            }
        }
        __syncthreads();
        // MFMA phase
        bf16x8 a0 = *(const bf16x8*)(&els[(w * 16 + lr) * 72 + 8 * ld]);       // k 0..31
        bf16x8 a1 = *(const bf16x8*)(&els[(w * 16 + lr) * 72 + 32 + 8 * ld]);  // k 32..63
        #pragma unroll
        for (int ct = 0; ct < 4; ++ct) {
            f32x4 acc = {0.f, 0.f, 0.f, 0.f};
            acc = __builtin_amdgcn_mfma_f32_16x16x32_bf16(a0, bfrag[ct][0], acc, 0, 0, 0);
            acc = __builtin_amdgcn_mfma_f32_16x16x32_bf16(a1, bfrag[ct][1], acc, 0, 0, 0);
            #pragma unroll
            for (int j = 0; j < 4; ++j) {
                int row = base + w * 16 + 4 * ld + j;
                if (row < E)
                    ecs[(size_t)row * DD + ct * 16 + lr] = f2bf(acc[j] + bcl[ct]);
            }
        }
    }
}

// ---------------------------------------------------------------------------
// fused node-centric accumulation: one WAVE per dst node, lane = channel.
// Eh on the fly (readlane matvec); per edge j: er = ecs[j] + D + Eh with
// (D,B) from one ushort2 gather of DBh; num/den in registers; es written
// back into ecs.  stats: [0:64) es | [64:128) es^2 | [128:192) x | [192:256) x^2
// ---------------------------------------------------------------------------
__global__ __launch_bounds__(256) void fused_accum_v8(
    bfu* __restrict__ ecs,
    const bfu* __restrict__ Ah, const bfu* __restrict__ DBh,
    const float* __restrict__ h, const float* __restrict__ We, const float* __restrict__ be,
    const int* __restrict__ coffs, const unsigned short* __restrict__ src_p,
    const float* __restrict__ enorm_p, const float* __restrict__ nnorm,
    float* __restrict__ hraw, float* __restrict__ stats, int N, int store_es)
{
    __shared__ float red[4][4][DD];
    int wid = threadIdx.x >> 6;
    int c   = threadIdx.x & 63;
    float wcol[DD];
    #pragma unroll
    for (int k = 0; k < DD; ++k) wcol[k] = We[k * DD + c];
    float bec = be[c];
    float se = 0.f, se2 = 0.f, sh = 0.f, sh2 = 0.f;

    int gw = blockIdx.x * 4 + wid;
    int gstride = gridDim.x * 4;
    for (int n = gw; n < N; n += gstride) {
        int j0 = coffs[n], j1 = coffs[n + 1];
        float hv = h[(size_t)n * DD + c];
        float e0 = bec, e1 = 0.f, e2 = 0.f, e3 = 0.f;
        #pragma unroll
        for (int k = 0; k < DD; k += 4) {
            e0 += readlane_f(hv, k)     * wcol[k];
            e1 += readlane_f(hv, k + 1) * wcol[k + 1];
            e2 += readlane_f(hv, k + 2) * wcol[k + 2];
            e3 += readlane_f(hv, k + 3) * wcol[k + 3];
        }
        float ehv = (e0 + e1) + (e2 + e3);
        float num = 0.f, den = 0.f;
        for (int j = j0; j < j1; ++j) {
            int s = src_p[j];
            float en = enorm_p[j];
            ushort2 db = *(const ushort2*)(DBh + (size_t)s * 128 + 2 * c);
            float er = bf2f(ecs[(size_t)j * DD + c]) + bf2f(db.x) + ehv;
            float sg = sigmoidf_(er);
            num += sg * bf2f(db.y);
            den += sg;
            float es = er * en;
            if (store_es) ecs[(size_t)j * DD + c] = f2bf(es);
            se += es; se2 += es * es;
        }
        float x = (bf2f(Ah[(size_t)n * DD + c]) + num / (den + 1e-6f)) * nnorm[n];
        hraw[(size_t)n * DD + c] = x;
        sh += x; sh2 += x * x;
    }

    red[wid][0][c] = se;  red[wid][1][c] = se2;
    red[wid][2][c] = sh;  red[wid][3][c] = sh2;
    __syncthreads();
    if (threadIdx.x < DD) {
        int t = threadIdx.x;
        float t0 = 0.f, t1 = 0.f, t2 = 0.f, t3 = 0.f;
        #pragma unroll
        for (int w = 0; w < 4; ++w) {
            t0 += red[w][0][t]; t1 += red[w][1][t];
            t2 += red[w][2][t]; t3 += red[w][3][t];
        }
        unsafeAtomicAdd(&stats[t], t0);
        unsafeAtomicAdd(&stats[DD + t], t1);
        unsafeAtomicAdd(&stats[2 * DD + t], t2);
        unsafeAtomicAdd(&stats[3 * DD + t], t3);
    }
}

// ---------------------------------------------------------------------------
__global__ void bn_fin2_v8(const float* __restrict__ stats, float Ecnt, float Ncnt,
                           float* __restrict__ bnp)
{
    int t = threadIdx.x;   // 128 threads
    if (t < DD) {
        float mu  = stats[t] / Ecnt;
        float var = stats[DD + t] / Ecnt - mu * mu;
        bnp[t] = mu;
        bnp[DD + t] = rsqrtf(var + 1e-5f);
    } else {
        int cc = t - DD;
        float mu  = stats[2 * DD + cc] / Ncnt;
        float var = stats[3 * DD + cc] / Ncnt - mu * mu;
        bnp[2 * DD + cc] = mu;
        bnp[3 * DD + cc] = rsqrtf(var + 1e-5f);
    }
}

// ---------------------------------------------------------------------------
__global__ __launch_bounds__(256) void node_apply_v8(
    const float* __restrict__ hraw, const float* __restrict__ bnph,
    const float* __restrict__ gamma, const float* __restrict__ beta,
    float* __restrict__ h, int N)
{
    int cc = (threadIdx.x & 15) * 4;
    float4 mu = *(const float4*)(bnph + cc);
    float4 is = *(const float4*)(bnph + DD + cc);
    float4 g  = *(const float4*)(gamma + cc);
    float4 b  = *(const float4*)(beta + cc);
    int total = N * 16;
    int stride = gridDim.x * blockDim.x;
    for (int u = blockIdx.x * blockDim.x + threadIdx.x; u < total; u += stride) {
        size_t off = ((size_t)(u >> 4)) * DD + ((u & 15) * 4);
        float4 x   = *(const float4*)(hraw + off);
        float4 hin = *(const float4*)(h + off);
        float4 y;
        y.x = hin.x + fmaxf(g.x * (x.x - mu.x) * is.x + b.x, 0.f);
        y.y = hin.y + fmaxf(g.y * (x.y - mu.y) * is.y + b.y, 0.f);
        y.z = hin.z + fmaxf(g.z * (x.z - mu.z) * is.z + b.z, 0.f);
        y.w = hin.w + fmaxf(g.w * (x.w - mu.w) * is.w + b.w, 0.f);
        *(float4*)(h + off) = y;
    }
}

// ---------------------------------------------------------------------------
__global__ __launch_bounds__(256) void readout_v8(
    const float* __restrict__ h, const int* __restrict__ gid,
    float* __restrict__ hg, float* __restrict__ counts, int N)
{
    int total = N * 16;
    int stride = gridDim.x * blockDim.x;
    for (int u = blockIdx.x * blockDim.x + threadIdx.x; u < total; u += stride) {
        int n = u >> 4;
        int c = (u & 15) * 4;
        int g = gid[n];
        float4 x = *(const float4*)(h + (size_t)n * DD + c);
        float* p = hg + (size_t)g * DD + c;
        unsafeAtomicAdd(p + 0, x.x);
        unsafeAtomicAdd(p + 1, x.y);
        unsafeAtomicAdd(p + 2, x.z);
        unsafeAtomicAdd(p + 3, x.w);
        if ((u & 15) == 0) unsafeAtomicAdd(&counts[g], 1.0f);
    }
}

__global__ void readout_div_v8(const float* __restrict__ hg,
                               const float* __restrict__ counts,
                               float* __restrict__ out, int GD)
{
    int i = blockIdx.x * blockDim.x + threadIdx.x;
    if (i < GD) {
        int g = i >> 6;
        out[i] = hg[i] / fmaxf(counts[g], 1.0f);
    }
}

// ---------------------------------------------------------------------------
extern "C" void kernel_launch(void* const* d_in, const int* in_sizes, int n_in,
                              void* d_out, int out_size, void* d_ws, size_t ws_size,
                              hipStream_t stream)
{
    const float* nodes_feat = (const float*)d_in[0];
    const float* edges_feat = (const float*)d_in[1];
    const float* nnorm      = (const float*)d_in[2];
    const float* enorm      = (const float*)d_in[3];
    const float* W_h = (const float*)d_in[4];
    const float* b_h = (const float*)d_in[5];
    const float* W_e = (const float*)d_in[6];
    const float* b_e = (const float*)d_in[7];
    const float* Wa  = (const float*)d_in[8];
    const float* ba  = (const float*)d_in[9];
    const float* Wb_ = (const float*)d_in[10];
    const float* bb_ = (const float*)d_in[11];
    const float* Wc  = (const float*)d_in[12];
    const float* bc  = (const float*)d_in[13];
    const float* Wd  = (const float*)d_in[14];
    const float* bd  = (const float*)d_in[15];
    const float* We_ = (const float*)d_in[16];
    const float* be_ = (const float*)d_in[17];
    const float* gamma_h = (const float*)d_in[18];
    const float* beta_h  = (const float*)d_in[19];
    const float* gamma_e = (const float*)d_in[20];
    const float* beta_e  = (const float*)d_in[21];
    const int* esrc = (const int*)d_in[22];
    const int* edst = (const int*)d_in[23];
    const int* gid  = (const int*)d_in[24];

    const int N = in_sizes[0] / DIN;
    const int E = in_sizes[1];
    const int G = out_size / DD;
    const int L = in_sizes[8] / (DD * DD);

    // ---- workspace layout (~254.7 MB) ----
    float* f = (float*)d_ws;
    float* h       = f; f += (size_t)N * DD;
    float* hraw    = f; f += (size_t)N * DD;
    float* stats   = f; f += 256;
    float* bnp     = f; f += 256;
    float* hg      = f; f += (size_t)G * DD;   // } zeroed together
    float* gcnt    = f; f += G;                // }
    int*   coffs   = (int*)f; f += (size_t)(N + 2);
    float* enorm_p = f; f += (size_t)E;
    unsigned short* src_p = (unsigned short*)f; f += (size_t)((E + 1) / 2);
    bfu* bp = (bfu*)f;
    bfu* Ah  = bp; bp += (size_t)N * DD;
    bfu* DBh = bp; bp += (size_t)N * 128;
    bfu* e_p = bp; bp += (size_t)E * DD;
    bfu* ecs = bp; bp += (size_t)E * DD;
    // setup-only CSR scratch overlays the ecs region (dead until layer 0 GEMM)
    int* ccounts = (int*)ecs;
    int* ccursor = ccounts + (N + 1);
    int* cpart   = ccursor + (N + 1);
    int* csr_eid = cpart + 256;

    dim3 blk(256);

    hipMemsetAsync(hg, 0, ((size_t)G * DD + G) * sizeof(float), stream);
    hipMemsetAsync(ccounts, 0, (size_t)(N + 1) * sizeof(int), stream);

    embed_h_v8<<<(N + 31) / 32, blk, 0, stream>>>(nodes_feat, W_h, b_h, h, N);

    const int M  = N + 1;
    const int CH = (M + 255) / 256;
    csr_hist_v8<<<2048, blk, 0, stream>>>(edst, ccounts, E);
    csr_scan_a_v8<<<256, blk, 0, stream>>>(ccounts, cpart, M, CH);
    csr_scan_b_v8<<<1, blk, 0, stream>>>(cpart);
    csr_scan_c_v8<<<256, blk, 0, stream>>>(ccounts, cpart, coffs, ccursor, M, CH);
    csr_scatter_v8<<<2048, blk, 0, stream>>>(edst, ccursor, csr_eid, E);
    perm_build_v8<<<2048, blk, 0, stream>>>(csr_eid, esrc, enorm, src_p, enorm_p, E);
    embed_e_perm_v8<<<2048, blk, 0, stream>>>(edges_feat, W_e, b_e, csr_eid, e_p, E);

    for (int l = 0; l < L; ++l) {
        node_mm3_v8<<<(N + 63) / 64, dim3(192), 0, stream>>>(
            h, Wa + (size_t)l * DD * DD, ba + (size_t)l * DD,
            Wb_ + (size_t)l * DD * DD, bb_ + (size_t)l * DD,
            Wd + (size_t)l * DD * DD, bd + (size_t)l * DD,
            Ah, DBh, N);
        hipMemsetAsync(stats, 0, 256 * sizeof(float), stream);
        ec_gemm_v8<<<2048, blk, 0, stream>>>(
            e_p, ecs, Wc + (size_t)l * DD * DD, bc + (size_t)l * DD,
            bnp,
            (l > 0) ? gamma_e + (size_t)(l - 1) * DD : gamma_e,
            (l > 0) ? beta_e  + (size_t)(l - 1) * DD : beta_e,
            (l > 0) ? 1 : 0,
            (l < L - 1) ? 1 : 0, E);
        fused_accum_v8<<<2048, blk, 0, stream>>>(
            ecs, Ah, DBh, h,
            We_ + (size_t)l * DD * DD, be_ + (size_t)l * DD,
            coffs, src_p, enorm_p, nnorm, hraw, stats, N,
            (l < L - 1) ? 1 : 0);
        bn_fin2_v8<<<1, 128, 0, stream>>>(stats, (float)E, (float)N, bnp);
        node_apply_v8<<<1024, blk, 0, stream>>>(
            hraw, bnp + 2 * DD,
            gamma_h + (size_t)l * DD, beta_h + (size_t)l * DD, h, N);
    }

    readout_v8<<<1024, blk, 0, stream>>>(h, gid, hg, gcnt, N);
    readout_div_v8<<<(G * DD + 255) / 256, blk, 0, stream>>>(
        hg, gcnt, (float*)d_out, G * DD);
}

// Round 9
// 1305.371 us; speedup vs baseline: 2.6149x; 1.1902x over previous
//
#include <hip/hip_runtime.h>
#include <cstddef>

#define DIN 128
#define DD 64

typedef unsigned short bfu;   // raw bf16 bits
typedef __attribute__((ext_vector_type(8))) short bf16x8;
typedef __attribute__((ext_vector_type(4))) float f32x4;

static __device__ __forceinline__ float bf2f(bfu u) {
    union { unsigned int i; float f; } v; v.i = ((unsigned int)u) << 16; return v.f;
}
static __device__ __forceinline__ bfu f2bf(float f) {
    union { float f; unsigned int i; } v; v.f = f;
    unsigned int r = v.i + 0x7FFFu + ((v.i >> 16) & 1u);   // round-nearest-even
    return (bfu)(r >> 16);
}
static __device__ __forceinline__ float4 bf4_to_f4(ushort4 u) {
    return make_float4(bf2f(u.x), bf2f(u.y), bf2f(u.z), bf2f(u.w));
}
static __device__ __forceinline__ ushort4 f4_to_bf4(float4 f) {
    ushort4 u; u.x = f2bf(f.x); u.y = f2bf(f.y); u.z = f2bf(f.z); u.w = f2bf(f.w); return u;
}
static __device__ __forceinline__ float sigmoidf_(float x) {
    return 1.0f / (1.0f + __expf(-x));
}

// ---------------------------------------------------------------------------
// h0 = nodes_feat @ W_h + b_h   [N,128]@[128,64] -> f32
// ---------------------------------------------------------------------------
__global__ __launch_bounds__(256) void embed_h_v9(
    const float* __restrict__ x, const float* __restrict__ Wh,
    const float* __restrict__ bh, float* __restrict__ h, int N)
{
    __shared__ float w[DIN][DD];    // 32 KB
    __shared__ float xs[32][DIN];   // 16 KB
    for (int i = threadIdx.x; i < DIN * DD / 4; i += 256)
        ((float4*)w)[i] = ((const float4*)Wh)[i];
    int row0 = blockIdx.x * 32;
    for (int i = threadIdx.x; i < 32 * DIN / 4; i += 256) {
        int r = i >> 5, k = (i & 31) * 4;
        int row = row0 + r;
        float4 v = make_float4(0.f, 0.f, 0.f, 0.f);
        if (row < N) v = *(const float4*)(x + (size_t)row * DIN + k);
        *(float4*)(&xs[r][k]) = v;
    }
    __syncthreads();
    int rl = threadIdx.x >> 6;
    int c  = threadIdx.x & 63;
    float b = bh[c];
    for (int rr = 0; rr < 8; ++rr) {
        int r = rl * 8 + rr;
        int row = row0 + r;
        if (row >= N) break;
        float acc = b;
        #pragma unroll
        for (int k = 0; k < DIN; k += 4) {
            float4 xv = *(const float4*)(&xs[r][k]);
            acc += xv.x * w[k][c] + xv.y * w[k+1][c] + xv.z * w[k+2][c] + xv.w * w[k+3][c];
        }
        h[(size_t)row * DD + c] = acc;
    }
}

// ---------------------------------------------------------------------------
// CSR build (by dst): histogram -> 3-phase exclusive scan -> scatter
// ---------------------------------------------------------------------------
__global__ void csr_hist_v9(const int* __restrict__ dst, int* __restrict__ counts, int E)
{
    for (int i = blockIdx.x * blockDim.x + threadIdx.x; i < E; i += gridDim.x * blockDim.x)
        atomicAdd(&counts[dst[i]], 1);
}

__global__ void csr_scan_a_v9(const int* __restrict__ counts, int* __restrict__ part,
                              int M, int CH)
{
    __shared__ int sd[256];
    int b = blockIdx.x, t = threadIdx.x;
    int idx = b * CH + t;
    int v = (t < CH && idx < M) ? counts[idx] : 0;
    sd[t] = v; __syncthreads();
    for (int off = 128; off > 0; off >>= 1) {
        if (t < off) sd[t] += sd[t + off];
        __syncthreads();
    }
    if (t == 0) part[b] = sd[0];
}

__global__ void csr_scan_b_v9(int* __restrict__ part)
{
    __shared__ int sd[256];
    int t = threadIdx.x;
    int v = part[t];
    sd[t] = v; __syncthreads();
    for (int off = 1; off < 256; off <<= 1) {
        int u = (t >= off) ? sd[t - off] : 0;
        __syncthreads();
        sd[t] += u;
        __syncthreads();
    }
    part[t] = sd[t] - v;   // exclusive
}

__global__ void csr_scan_c_v9(const int* __restrict__ counts, const int* __restrict__ part,
                              int* __restrict__ offsets, int* __restrict__ cursor,
                              int M, int CH)
{
    __shared__ int sd[256];
    int b = blockIdx.x, t = threadIdx.x;
    int idx = b * CH + t;
    int v = (t < CH && idx < M) ? counts[idx] : 0;
    sd[t] = v; __syncthreads();
    for (int off = 1; off < 256; off <<= 1) {
        int u = (t >= off) ? sd[t - off] : 0;
        __syncthreads();
        sd[t] += u;
        __syncthreads();
    }
    int excl = sd[t] - v + part[b];
    if (t < CH && idx < M) { offsets[idx] = excl; cursor[idx] = excl; }
}

__global__ void csr_scatter_v9(const int* __restrict__ dst, int* __restrict__ cursor,
                               int* __restrict__ csr_eid, int E)
{
    for (int i = blockIdx.x * blockDim.x + threadIdx.x; i < E; i += gridDim.x * blockDim.x) {
        int p = atomicAdd(&cursor[dst[i]], 1);
        csr_eid[p] = i;
    }
}

__global__ void perm_build_v9(const int* __restrict__ csr_eid, const int* __restrict__ esrc,
                              const float* __restrict__ enorm,
                              unsigned short* __restrict__ src_p,
                              float* __restrict__ enorm_p, int E)
{
    for (int i = blockIdx.x * blockDim.x + threadIdx.x; i < E; i += gridDim.x * blockDim.x) {
        int eid = csr_eid[i];
        src_p[i] = (unsigned short)esrc[eid];
        enorm_p[i] = enorm[eid];
    }
}

__global__ __launch_bounds__(256) void embed_e_perm_v9(
    const float* __restrict__ ef, const float* __restrict__ We,
    const float* __restrict__ be, const int* __restrict__ csr_eid,
    bfu* __restrict__ e, int E)
{
    int c = (threadIdx.x & 15) * 4;
    float4 w = *(const float4*)(We + c);
    float4 b = *(const float4*)(be + c);
    int total = E * 16;
    int stride = gridDim.x * blockDim.x;
    for (int u = blockIdx.x * blockDim.x + threadIdx.x; u < total; u += stride) {
        int j = u >> 4;
        float f = ef[csr_eid[j]];
        float4 o;
        o.x = f * w.x + b.x; o.y = f * w.y + b.y;
        o.z = f * w.z + b.z; o.w = f * w.w + b.w;
        *(ushort4*)(e + (size_t)j * DD + c) = f4_to_bf4(o);
    }
}

// ---------------------------------------------------------------------------
// node_mm4: 4 waves, one per matrix. wave0: Ah -> hrawA (f32);
// wave1: Bh -> DBh[2c+1]; wave2: Dh -> DBh[2c]; wave3: Eh -> Eh buf (bf16)
// ---------------------------------------------------------------------------
__global__ __launch_bounds__(256) void node_mm4_v9(
    const float* __restrict__ h,
    const float* __restrict__ Wa, const float* __restrict__ ba,
    const float* __restrict__ Wb, const float* __restrict__ bbv,
    const float* __restrict__ Wd, const float* __restrict__ bd,
    const float* __restrict__ We, const float* __restrict__ be,
    float* __restrict__ hrawA, bfu* __restrict__ DBh, bfu* __restrict__ Eh, int N)
{
    __shared__ float hs[64][DD];   // 16 KB
    int row0 = blockIdx.x * 64;
    for (int i = threadIdx.x; i < 64 * 16; i += 256) {
        int r = i >> 4, cc = (i & 15) * 4;
        int row = row0 + r;
        float4 v = make_float4(0.f, 0.f, 0.f, 0.f);
        if (row < N) v = *(const float4*)(h + (size_t)row * DD + cc);
        *(float4*)(&hs[r][cc]) = v;
    }
    __syncthreads();
    int m = threadIdx.x >> 6;
    int c = threadIdx.x & 63;
    const float* W    = (m == 0) ? Wa : (m == 1) ? Wb : (m == 2) ? Wd : We;
    const float* bias = (m == 0) ? ba : (m == 1) ? bbv : (m == 2) ? bd : be;
    float wcol[DD];
    #pragma unroll
    for (int k = 0; k < DD; ++k) wcol[k] = W[k * DD + c];
    float b = bias[c];
    int rmax = (N - row0 < 64) ? (N - row0) : 64;
    for (int r = 0; r < rmax; ++r) {
        float acc = b;
        #pragma unroll
        for (int k = 0; k < DD; k += 4) {
            float4 hv = *(const float4*)(&hs[r][k]);
            acc += hv.x * wcol[k] + hv.y * wcol[k+1] + hv.z * wcol[k+2] + hv.w * wcol[k+3];
        }
        size_t row = (size_t)(row0 + r);
        if (m == 0)      hrawA[row * DD + c] = acc;                // Ah (f32)
        else if (m == 1) DBh[row * 128 + 2 * c + 1] = f2bf(acc);   // B
        else if (m == 2) DBh[row * 128 + 2 * c] = f2bf(acc);       // D
        else             Eh[row * DD + c] = f2bf(acc);             // E
    }
}

// ---------------------------------------------------------------------------
// ec_gemm v9 (MFMA, LDS-free): wave owns a 16-edge tile.
//   A-frag: lane l = row (l&15), k = 8*(l>>4)+j  -> contiguous 16B loads.
//   apply: e_new = e + relu(A*es + B) (A,B per channel from bnAB), store e,
//   feed MFMA. C/D: col = ct*16 + (l&15), row = 4*(l>>4)+j.
// ---------------------------------------------------------------------------
__global__ __launch_bounds__(256) void ec_gemm_v9(
    bfu* __restrict__ e, bfu* __restrict__ ecs,
    const float* __restrict__ Wc, const float* __restrict__ bc,
    const float* __restrict__ bnAB,   // [0:64) A_e, [64:128) B_e
    int apply, int store_e, int E)
{
    int l  = threadIdx.x & 63;
    int lr = l & 15;
    int ld = l >> 4;

    bf16x8 bfrag[4][2];
    #pragma unroll
    for (int ct = 0; ct < 4; ++ct)
        #pragma unroll
        for (int kh = 0; kh < 2; ++kh)
            #pragma unroll
            for (int j = 0; j < 8; ++j)
                bfrag[ct][kh][j] = (short)f2bf(Wc[(kh * 32 + 8 * ld + j) * DD + ct * 16 + lr]);

    float bcl[4];
    #pragma unroll
    for (int ct = 0; ct < 4; ++ct) bcl[ct] = bc[ct * 16 + lr];

    float A0[8], B0[8], A1[8], B1[8];
    if (apply) {
        #pragma unroll
        for (int j = 0; j < 8; ++j) {
            A0[j] = bnAB[8 * ld + j];
            B0[j] = bnAB[64 + 8 * ld + j];
            A1[j] = bnAB[32 + 8 * ld + j];
            B1[j] = bnAB[64 + 32 + 8 * ld + j];
        }
    }

    int wg = blockIdx.x * 4 + (threadIdx.x >> 6);
    int nw = gridDim.x * 4;
    for (int base = wg * 16; base < E; base += nw * 16) {
        int row = base + lr;
        bf16x8 a0 = {0, 0, 0, 0, 0, 0, 0, 0};
        bf16x8 a1 = {0, 0, 0, 0, 0, 0, 0, 0};
        if (row < E) {
            size_t off = (size_t)row * DD + 8 * ld;
            bf16x8 r0 = *(const bf16x8*)(e + off);
            bf16x8 r1 = *(const bf16x8*)(e + off + 32);
            if (apply) {
                bf16x8 s0 = *(const bf16x8*)(ecs + off);
                bf16x8 s1 = *(const bf16x8*)(ecs + off + 32);
                #pragma unroll
                for (int j = 0; j < 8; ++j) {
                    float v0 = bf2f((bfu)r0[j]) + fmaxf(A0[j] * bf2f((bfu)s0[j]) + B0[j], 0.f);
                    float v1 = bf2f((bfu)r1[j]) + fmaxf(A1[j] * bf2f((bfu)s1[j]) + B1[j], 0.f);
                    a0[j] = (short)f2bf(v0);
                    a1[j] = (short)f2bf(v1);
                }
                if (store_e) {
                    *(bf16x8*)(e + off) = a0;
                    *(bf16x8*)(e + off + 32) = a1;
                }
            } else {
                a0 = r0; a1 = r1;
            }
        }
        #pragma unroll
        for (int ct = 0; ct < 4; ++ct) {
            f32x4 acc = {0.f, 0.f, 0.f, 0.f};
            acc = __builtin_amdgcn_mfma_f32_16x16x32_bf16(a0, bfrag[ct][0], acc, 0, 0, 0);
            acc = __builtin_amdgcn_mfma_f32_16x16x32_bf16(a1, bfrag[ct][1], acc, 0, 0, 0);
            #pragma unroll
            for (int j = 0; j < 4; ++j) {
                int orow = base + 4 * ld + j;
                if (orow < E)
                    ecs[(size_t)orow * DD + ct * 16 + lr] = f2bf(acc[j] + bcl[ct]);
            }
        }
    }
}

// ---------------------------------------------------------------------------
// fused node-centric accumulation: one WAVE per dst node, lane = channel.
// Reads Ah (f32) from hrawA, Eh (bf16); per edge: er = ecs + D + Eh with
// (D,B) one ushort2 gather; 2x unrolled; es written back into ecs.
// stats: [0:64) es | [64:128) es^2 | [128:192) x | [192:256) x^2
// ---------------------------------------------------------------------------
__global__ __launch_bounds__(256) void fused_accum_v9(
    bfu* __restrict__ ecs, float* __restrict__ hrawA,
    const bfu* __restrict__ DBh, const bfu* __restrict__ Eh,
    const int* __restrict__ coffs, const unsigned short* __restrict__ src_p,
    const float* __restrict__ enorm_p, const float* __restrict__ nnorm,
    float* __restrict__ stats, int N, int store_es)
{
    __shared__ float red[4][4][DD];
    int wid = threadIdx.x >> 6;
    int c   = threadIdx.x & 63;
    float se0 = 0.f, se20 = 0.f, se1 = 0.f, se21 = 0.f;
    float sh = 0.f, sh2 = 0.f;

    int gw = blockIdx.x * 4 + wid;
    int gstride = gridDim.x * 4;
    for (int n = gw; n < N; n += gstride) {
        int j0 = coffs[n], j1 = coffs[n + 1];
        float ehv = bf2f(Eh[(size_t)n * DD + c]);
        float a = hrawA[(size_t)n * DD + c];
        float num0 = 0.f, den0 = 0.f, num1 = 0.f, den1 = 0.f;
        int j = j0;
        for (; j + 1 < j1; j += 2) {
            int s0 = src_p[j], s1 = src_p[j + 1];
            float en0 = enorm_p[j], en1 = enorm_p[j + 1];
            bfu ec0 = ecs[(size_t)j * DD + c];
            bfu ec1 = ecs[(size_t)(j + 1) * DD + c];
            ushort2 db0 = *(const ushort2*)(DBh + (size_t)s0 * 128 + 2 * c);
            ushort2 db1 = *(const ushort2*)(DBh + (size_t)s1 * 128 + 2 * c);
            float er0 = bf2f(ec0) + bf2f(db0.x) + ehv;
            float er1 = bf2f(ec1) + bf2f(db1.x) + ehv;
            float sg0 = sigmoidf_(er0);
            float sg1 = sigmoidf_(er1);
            num0 += sg0 * bf2f(db0.y); den0 += sg0;
            num1 += sg1 * bf2f(db1.y); den1 += sg1;
            float es0 = er0 * en0, es1 = er1 * en1;
            if (store_es) {
                ecs[(size_t)j * DD + c] = f2bf(es0);
                ecs[(size_t)(j + 1) * DD + c] = f2bf(es1);
            }
            se0 += es0; se20 += es0 * es0;
            se1 += es1; se21 += es1 * es1;
        }
        if (j < j1) {
            int s0 = src_p[j];
            float en0 = enorm_p[j];
            bfu ec0 = ecs[(size_t)j * DD + c];
            ushort2 db0 = *(const ushort2*)(DBh + (size_t)s0 * 128 + 2 * c);
            float er0 = bf2f(ec0) + bf2f(db0.x) + ehv;
            float sg0 = sigmoidf_(er0);
            num0 += sg0 * bf2f(db0.y); den0 += sg0;
            float es0 = er0 * en0;
            if (store_es) ecs[(size_t)j * DD + c] = f2bf(es0);
            se0 += es0; se20 += es0 * es0;
        }
        float x = (a + (num0 + num1) / ((den0 + den1) + 1e-6f)) * nnorm[n];
        hrawA[(size_t)n * DD + c] = x;
        sh += x; sh2 += x * x;
    }

    red[wid][0][c] = se0 + se1;  red[wid][1][c] = se20 + se21;
    red[wid][2][c] = sh;         red[wid][3][c] = sh2;
    __syncthreads();
    if (threadIdx.x < DD) {
        int t = threadIdx.x;
        float t0 = 0.f, t1 = 0.f, t2 = 0.f, t3 = 0.f;
        #pragma unroll
        for (int w = 0; w < 4; ++w) {
            t0 += red[w][0][t]; t1 += red[w][1][t];
            t2 += red[w][2][t]; t3 += red[w][3][t];
        }
        unsafeAtomicAdd(&stats[t], t0);
        unsafeAtomicAdd(&stats[DD + t], t1);
        unsafeAtomicAdd(&stats[2 * DD + t], t2);
        unsafeAtomicAdd(&stats[3 * DD + t], t3);
    }
}

// ---------------------------------------------------------------------------
// finalize both BNs into fused scale/shift:
// bnAB: [0:64)=A_e [64:128)=B_e [128:192)=A_h [192:256)=B_h
// where A=gamma*istd, B=beta-A*mu
// ---------------------------------------------------------------------------
__global__ void bn_fin2_v9(const float* __restrict__ stats, float Ecnt, float Ncnt,
                           const float* __restrict__ gamma_e, const float* __restrict__ beta_e,
                           const float* __restrict__ gamma_h, const float* __restrict__ beta_h,
                           float* __restrict__ bnAB)
{
    int t = threadIdx.x;   // 128 threads
    if (t < DD) {
        float mu  = stats[t] / Ecnt;
        float var = stats[DD + t] / Ecnt - mu * mu;
        float A = gamma_e[t] * rsqrtf(var + 1e-5f);
        bnAB[t] = A;
        bnAB[DD + t] = beta_e[t] - A * mu;
    } else {
        int cc = t - DD;
        float mu  = stats[2 * DD + cc] / Ncnt;
        float var = stats[3 * DD + cc] / Ncnt - mu * mu;
        float A = gamma_h[cc] * rsqrtf(var + 1e-5f);
        bnAB[2 * DD + cc] = A;
        bnAB[3 * DD + cc] = beta_h[cc] - A * mu;
    }
}

// ---------------------------------------------------------------------------
// h = h + relu(A*x + B); h, x(=hrawA) f32.
// ---------------------------------------------------------------------------
__global__ __launch_bounds__(256) void node_apply_v9(
    const float* __restrict__ hrawA, const float* __restrict__ bnAB,
    float* __restrict__ h, int N)
{
    int cc = (threadIdx.x & 15) * 4;
    float4 A = *(const float4*)(bnAB + 2 * DD + cc);
    float4 B = *(const float4*)(bnAB + 3 * DD + cc);
    int total = N * 16;
    int stride = gridDim.x * blockDim.x;
    for (int u = blockIdx.x * blockDim.x + threadIdx.x; u < total; u += stride) {
        size_t off = ((size_t)(u >> 4)) * DD + ((u & 15) * 4);
        float4 x   = *(const float4*)(hrawA + off);
        float4 hin = *(const float4*)(h + off);
        float4 y;
        y.x = hin.x + fmaxf(A.x * x.x + B.x, 0.f);
        y.y = hin.y + fmaxf(A.y * x.y + B.y, 0.f);
        y.z = hin.z + fmaxf(A.z * x.z + B.z, 0.f);
        y.w = hin.w + fmaxf(A.w * x.w + B.w, 0.f);
        *(float4*)(h + off) = y;
    }
}

// ---------------------------------------------------------------------------
__global__ __launch_bounds__(256) void readout_v9(
    const float* __restrict__ h, const int* __restrict__ gid,
    float* __restrict__ hg, float* __restrict__ counts, int N)
{
    int total = N * 16;
    int stride = gridDim.x * blockDim.x;
    for (int u = blockIdx.x * blockDim.x + threadIdx.x; u < total; u += stride) {
        int n = u >> 4;
        int c = (u & 15) * 4;
        int g = gid[n];
        float4 x = *(const float4*)(h + (size_t)n * DD + c);
        float* p = hg + (size_t)g * DD + c;
        unsafeAtomicAdd(p + 0, x.x);
        unsafeAtomicAdd(p + 1, x.y);
        unsafeAtomicAdd(p + 2, x.z);
        unsafeAtomicAdd(p + 3, x.w);
        if ((u & 15) == 0) unsafeAtomicAdd(&counts[g], 1.0f);
    }
}

__global__ void readout_div_v9(const float* __restrict__ hg,
                               const float* __restrict__ counts,
                               float* __restrict__ out, int GD)
{
    int i = blockIdx.x * blockDim.x + threadIdx.x;
    if (i < GD) {
        int g = i >> 6;
        out[i] = hg[i] / fmaxf(counts[g], 1.0f);
    }
}

// ---------------------------------------------------------------------------
extern "C" void kernel_launch(void* const* d_in, const int* in_sizes, int n_in,
                              void* d_out, int out_size, void* d_ws, size_t ws_size,
                              hipStream_t stream)
{
    const float* nodes_feat = (const float*)d_in[0];
    const float* edges_feat = (const float*)d_in[1];
    const float* nnorm      = (const float*)d_in[2];
    const float* enorm      = (const float*)d_in[3];
    const float* W_h = (const float*)d_in[4];
    const float* b_h = (const float*)d_in[5];
    const float* W_e = (const float*)d_in[6];
    const float* b_e = (const float*)d_in[7];
    const float* Wa  = (const float*)d_in[8];
    const float* ba  = (const float*)d_in[9];
    const float* Wb_ = (const float*)d_in[10];
    const float* bb_ = (const float*)d_in[11];
    const float* Wc  = (const float*)d_in[12];
    const float* bc  = (const float*)d_in[13];
    const float* Wd  = (const float*)d_in[14];
    const float* bd  = (const float*)d_in[15];
    const float* We_ = (const float*)d_in[16];
    const float* be_ = (const float*)d_in[17];
    const float* gamma_h = (const float*)d_in[18];
    const float* beta_h  = (const float*)d_in[19];
    const float* gamma_e = (const float*)d_in[20];
    const float* beta_e  = (const float*)d_in[21];
    const int* esrc = (const int*)d_in[22];
    const int* edst = (const int*)d_in[23];
    const int* gid  = (const int*)d_in[24];

    const int N = in_sizes[0] / DIN;
    const int E = in_sizes[1];
    const int G = out_size / DD;
    const int L = in_sizes[8] / (DD * DD);

    // ---- workspace layout (~254.7 MB) ----
    float* f = (float*)d_ws;
    float* h       = f; f += (size_t)N * DD;
    float* hrawA   = f; f += (size_t)N * DD;     // Ah (in) / x (out), f32
    float* stats   = f; f += 256;
    float* bnAB    = f; f += 256;
    float* hg      = f; f += (size_t)G * DD;   // } zeroed together
    float* gcnt    = f; f += G;                // }
    int*   coffs   = (int*)f; f += (size_t)(N + 2);
    float* enorm_p = f; f += (size_t)E;
    unsigned short* src_p = (unsigned short*)f; f += (size_t)((E + 1) / 2);
    bfu* bp = (bfu*)f;
    bfu* DBh = bp; bp += (size_t)N * 128;
    bfu* Eh  = bp; bp += (size_t)N * DD;
    bfu* e_p = bp; bp += (size_t)E * DD;
    bfu* ecs = bp; bp += (size_t)E * DD;
    // setup-only CSR scratch overlays the ecs region (dead until layer 0 GEMM)
    int* ccounts = (int*)ecs;
    int* ccursor = ccounts + (N + 1);
    int* cpart   = ccursor + (N + 1);
    int* csr_eid = cpart + 256;

    dim3 blk(256);

    hipMemsetAsync(hg, 0, ((size_t)G * DD + G) * sizeof(float), stream);
    hipMemsetAsync(ccounts, 0, (size_t)(N + 1) * sizeof(int), stream);

    embed_h_v9<<<(N + 31) / 32, blk, 0, stream>>>(nodes_feat, W_h, b_h, h, N);

    const int M  = N + 1;
    const int CH = (M + 255) / 256;
    csr_hist_v9<<<2048, blk, 0, stream>>>(edst, ccounts, E);
    csr_scan_a_v9<<<256, blk, 0, stream>>>(ccounts, cpart, M, CH);
    csr_scan_b_v9<<<1, blk, 0, stream>>>(cpart);
    csr_scan_c_v9<<<256, blk, 0, stream>>>(ccounts, cpart, coffs, ccursor, M, CH);
    csr_scatter_v9<<<2048, blk, 0, stream>>>(edst, ccursor, csr_eid, E);
    perm_build_v9<<<2048, blk, 0, stream>>>(csr_eid, esrc, enorm, src_p, enorm_p, E);
    embed_e_perm_v9<<<2048, blk, 0, stream>>>(edges_feat, W_e, b_e, csr_eid, e_p, E);

    for (int l = 0; l < L; ++l) {
        node_mm4_v9<<<(N + 63) / 64, blk, 0, stream>>>(
            h, Wa + (size_t)l * DD * DD, ba + (size_t)l * DD,
            Wb_ + (size_t)l * DD * DD, bb_ + (size_t)l * DD,
            Wd + (size_t)l * DD * DD, bd + (size_t)l * DD,
            We_ + (size_t)l * DD * DD, be_ + (size_t)l * DD,
            hrawA, DBh, Eh, N);
        hipMemsetAsync(stats, 0, 256 * sizeof(float), stream);
        ec_gemm_v9<<<2048, blk, 0, stream>>>(
            e_p, ecs, Wc + (size_t)l * DD * DD, bc + (size_t)l * DD,
            bnAB,
            (l > 0) ? 1 : 0,
            (l < L - 1) ? 1 : 0, E);
        fused_accum_v9<<<2048, blk, 0, stream>>>(
            ecs, hrawA, DBh, Eh,
            coffs, src_p, enorm_p, nnorm, stats, N,
            (l < L - 1) ? 1 : 0);
        bn_fin2_v9<<<1, 128, 0, stream>>>(
            stats, (float)E, (float)N,
            gamma_e + (size_t)l * DD, beta_e + (size_t)l * DD,
            gamma_h + (size_t)l * DD, beta_h + (size_t)l * DD, bnAB);
        node_apply_v9<<<1024, blk, 0, stream>>>(hrawA, bnAB, h, N);
    }

    readout_v9<<<1024, blk, 0, stream>>>(h, gid, hg, gcnt, N);
    readout_div_v9<<<(G * DD + 255) / 256, blk, 0, stream>>>(
        hg, gcnt, (float*)d_out, G * DD);
}